// Round 1
// baseline (2466.198 us; speedup 1.0000x reference)
//
#include <hip/hip_runtime.h>
#include <math.h>

#define NN 100000
#define NE 1600000
#define DH 64
#define DO 40

// ---- degree accumulation: deg[row[e]] += w[e] ----
__global__ void deg_kernel(const int* __restrict__ row, const float* __restrict__ w,
                           float* __restrict__ deg) {
    int e = blockIdx.x * blockDim.x + threadIdx.x;
    if (e < NE) atomicAdd(&deg[row[e]], w[e]);
}

// ---- dinv = deg > 0 ? deg^-0.5 : 0 (in place) ----
__global__ void dinv_kernel(float* __restrict__ deg) {
    int i = blockIdx.x * blockDim.x + threadIdx.x;
    if (i < NN) {
        float d = deg[i];
        deg[i] = d > 0.f ? 1.0f / sqrtf(d) : 0.f;
    }
}

// ---- per-edge norm = -(2/lambda_max) * dinv[row] * w * dinv[col]; lambda_max=2 ----
__global__ void norm_kernel(const int* __restrict__ row, const int* __restrict__ col,
                            const float* __restrict__ w, const float* __restrict__ dinv,
                            float* __restrict__ nv) {
    int e = blockIdx.x * blockDim.x + threadIdx.x;
    if (e < NE) nv[e] = -dinv[row[e]] * w[e] * dinv[col[e]];
}

// ---- SpMV: y[row] += nv * h[col]  (diag term is 0 when lambda_max=2) ----
// one 64-lane group per edge (lane = feature), grid-stride over edges
__global__ void spmv_kernel(const int* __restrict__ row, const int* __restrict__ col,
                            const float* __restrict__ nv, const float* __restrict__ h,
                            float* __restrict__ y) {
    int g = blockIdx.x * blockDim.x + threadIdx.x;
    int grp = g >> 6, lane = g & 63;
    int ngrp = (gridDim.x * blockDim.x) >> 6;
    for (int e = grp; e < NE; e += ngrp) {
        int c = col[e], r = row[e];
        float nrm = nv[e];
        atomicAdd(&y[r * DH + lane], nrm * h[c * DH + lane]);
    }
}

// ---- fused: out = relu(Tx0@W[0] + Tx1@W[1] + (2*y2 - Tx0)@W[2] + b) ----
// W flat layout [3][64][DOUT]; thread = (node-in-block, out-feature)
template<int DOUT, int NPB>
__global__ __launch_bounds__(DOUT * NPB)
void gemm_kernel(const float* __restrict__ tx0g, const float* __restrict__ y1g,
                 const float* __restrict__ y2g, const float* __restrict__ Wg,
                 const float* __restrict__ bg, float* __restrict__ outg) {
    __shared__ float Ws[3 * DH * DOUT];
    __shared__ float tx[NPB][3][DH];
    const int nthr = DOUT * NPB;
    int tid = threadIdx.x;
    for (int i = tid; i < 3 * DH * DOUT; i += nthr) Ws[i] = Wg[i];
    int ln = tid / DOUT;
    int o = tid - ln * DOUT;
    float bias = bg[o];
    for (int base = blockIdx.x * NPB; base < NN; base += gridDim.x * NPB) {
        __syncthreads();  // Ws ready (1st iter) / tx reads done (later iters)
        for (int i = tid; i < NPB * DH; i += nthr) {
            int l = i >> 6, f = i & 63;
            int n = base + l;
            float a0 = 0.f, a1 = 0.f, a2 = 0.f;
            if (n < NN) {
                a0 = tx0g[n * DH + f];
                a1 = y1g[n * DH + f];
                a2 = 2.f * y2g[n * DH + f] - a0;  // Tx2 = 2*L(Tx1) - Tx0
            }
            tx[l][0][f] = a0;
            tx[l][1][f] = a1;
            tx[l][2][f] = a2;
        }
        __syncthreads();
        int n = base + ln;
        if (n < NN) {
            float acc = bias;
            #pragma unroll
            for (int i = 0; i < DH; ++i) {
                acc = fmaf(tx[ln][0][i], Ws[i * DOUT + o], acc);
                acc = fmaf(tx[ln][1][i], Ws[(DH + i) * DOUT + o], acc);
                acc = fmaf(tx[ln][2][i], Ws[(2 * DH + i) * DOUT + o], acc);
            }
            acc = fmaxf(acc, 0.f);  // reference applies relu after every layer
            outg[n * DOUT + o] = acc;
        }
    }
}

// ---- in-place log_softmax over last dim (40), one 64-lane group per node ----
__global__ void lsm_kernel(float* __restrict__ out) {
    int g = blockIdx.x * blockDim.x + threadIdx.x;
    int node = g >> 6, lane = g & 63;
    if (node >= NN) return;
    float v = lane < DO ? out[node * DO + lane] : -INFINITY;
    float m = v;
    #pragma unroll
    for (int off = 32; off > 0; off >>= 1) m = fmaxf(m, __shfl_xor(m, off));
    float ex = lane < DO ? __expf(v - m) : 0.f;
    float s = ex;
    #pragma unroll
    for (int off = 32; off > 0; off >>= 1) s += __shfl_xor(s, off);
    if (lane < DO) out[node * DO + lane] = v - m - __logf(s);
}

extern "C" void kernel_launch(void* const* d_in, const int* in_sizes, int n_in,
                              void* d_out, int out_size, void* d_ws, size_t ws_size,
                              hipStream_t stream) {
    const float* x  = (const float*)d_in[0];
    const int*   ei = (const int*)d_in[1];   // [2][E] int32
    const float* ea = (const float*)d_in[2];
    const float* W0 = (const float*)d_in[3];
    const float* b0 = (const float*)d_in[4];
    const float* W1 = (const float*)d_in[5];
    const float* b1 = (const float*)d_in[6];
    const float* W2 = (const float*)d_in[7];
    const float* b2 = (const float*)d_in[8];
    float* out = (float*)d_out;

    const int* row = ei;        // edge_index[0]
    const int* col = ei + NE;   // edge_index[1]

    char* p = (char*)d_ws;
    float* deg = (float*)p; p += (size_t)NN * 4;        // reused as dinv
    float* nv  = (float*)p; p += (size_t)NE * 4;
    float* y1  = (float*)p; p += (size_t)NN * DH * 4;
    float* y2  = (float*)p; p += (size_t)NN * DH * 4;
    float* hA  = (float*)p; p += (size_t)NN * DH * 4;
    float* hB  = (float*)p; p += (size_t)NN * DH * 4;

    hipMemsetAsync(deg, 0, (size_t)NN * 4, stream);
    deg_kernel<<<(NE + 255) / 256, 256, 0, stream>>>(row, ea, deg);
    dinv_kernel<<<(NN + 255) / 256, 256, 0, stream>>>(deg);
    norm_kernel<<<(NE + 255) / 256, 256, 0, stream>>>(row, col, ea, deg, nv);

    const int SPMV_BLOCKS = 8192;
    const size_t HBYTES = (size_t)NN * DH * 4;

    // ---- layer 0 (h = x) ----
    hipMemsetAsync(y1, 0, HBYTES, stream);
    spmv_kernel<<<SPMV_BLOCKS, 256, 0, stream>>>(row, col, nv, x, y1);
    hipMemsetAsync(y2, 0, HBYTES, stream);
    spmv_kernel<<<SPMV_BLOCKS, 256, 0, stream>>>(row, col, nv, y1, y2);
    gemm_kernel<DH, 4><<<2500, DH * 4, 0, stream>>>(x, y1, y2, W0, b0, hA);

    // ---- layer 1 (h = hA) ----
    hipMemsetAsync(y1, 0, HBYTES, stream);
    spmv_kernel<<<SPMV_BLOCKS, 256, 0, stream>>>(row, col, nv, hA, y1);
    hipMemsetAsync(y2, 0, HBYTES, stream);
    spmv_kernel<<<SPMV_BLOCKS, 256, 0, stream>>>(row, col, nv, y1, y2);
    gemm_kernel<DH, 4><<<2500, DH * 4, 0, stream>>>(hA, y1, y2, W1, b1, hB);

    // ---- layer 2 (h = hB) -> logits straight into d_out ----
    hipMemsetAsync(y1, 0, HBYTES, stream);
    spmv_kernel<<<SPMV_BLOCKS, 256, 0, stream>>>(row, col, nv, hB, y1);
    hipMemsetAsync(y2, 0, HBYTES, stream);
    spmv_kernel<<<SPMV_BLOCKS, 256, 0, stream>>>(row, col, nv, y1, y2);
    gemm_kernel<DO, 8><<<2500, DO * 8, 0, stream>>>(hB, y1, y2, W2, b2, out);

    // ---- log_softmax in place on d_out ----
    lsm_kernel<<<(NN * 64 + 255) / 256, 256, 0, stream>>>(out);
}

// Round 2
// 1192.871 us; speedup vs baseline: 2.0674x; 2.0674x over previous
//
#include <hip/hip_runtime.h>
#include <math.h>

#define NN 100000
#define NE 1600000
#define DH 64
#define DO 40
#define SCAN_BS 1024
#define SCAN_NB ((NN + SCAN_BS - 1) / SCAN_BS)   // 98

// ---- deg[row] += w  and  cnt[row] += 1 ----
__global__ void deg_hist_kernel(const int* __restrict__ row, const float* __restrict__ w,
                                float* __restrict__ deg, int* __restrict__ cnt) {
    int e = blockIdx.x * blockDim.x + threadIdx.x;
    if (e < NE) {
        int r = row[e];
        atomicAdd(&deg[r], w[e]);
        atomicAdd(&cnt[r], 1);
    }
}

// ---- dinv = deg > 0 ? deg^-0.5 : 0 (in place) ----
__global__ void dinv_kernel(float* __restrict__ deg) {
    int i = blockIdx.x * blockDim.x + threadIdx.x;
    if (i < NN) {
        float d = deg[i];
        deg[i] = d > 0.f ? 1.0f / sqrtf(d) : 0.f;
    }
}

// ---- block-level exclusive scan of cnt (Hillis-Steele in LDS) ----
__global__ __launch_bounds__(SCAN_BS) void scan_block_kernel(const int* __restrict__ cnt,
                                                             int* __restrict__ excl,
                                                             int* __restrict__ bsum) {
    __shared__ int tmp[SCAN_BS];
    int tid = threadIdx.x;
    int i = blockIdx.x * SCAN_BS + tid;
    int v = (i < NN) ? cnt[i] : 0;
    tmp[tid] = v;
    __syncthreads();
    for (int off = 1; off < SCAN_BS; off <<= 1) {
        int t = (tid >= off) ? tmp[tid - off] : 0;
        __syncthreads();
        tmp[tid] += t;
        __syncthreads();
    }
    if (i < NN) excl[i] = tmp[tid] - v;
    if (tid == SCAN_BS - 1) bsum[blockIdx.x] = tmp[tid];
}

// ---- serial scan of the 98 block sums (tiny) ----
__global__ void scan_bsum_kernel(int* __restrict__ bsum) {
    if (threadIdx.x == 0 && blockIdx.x == 0) {
        int run = 0;
        for (int j = 0; j < SCAN_NB; ++j) { int t = bsum[j]; bsum[j] = run; run += t; }
    }
}

// ---- ptr[i] = excl[i] + bsum[i/1024]; ptr[NN] = NE ----
__global__ void ptr_kernel(const int* __restrict__ excl, const int* __restrict__ bsum,
                           int* __restrict__ ptr) {
    int i = blockIdx.x * blockDim.x + threadIdx.x;
    if (i < NN) ptr[i] = excl[i] + bsum[i >> 10];
    if (i == 0) ptr[NN] = NE;
}

// ---- scatter edges into CSR order; fold in norm computation ----
__global__ void scatter_kernel(const int* __restrict__ row, const int* __restrict__ col,
                               const float* __restrict__ w, const float* __restrict__ dinv,
                               const int* __restrict__ ptr, int* __restrict__ fill,
                               int* __restrict__ ecol, float* __restrict__ env) {
    int e = blockIdx.x * blockDim.x + threadIdx.x;
    if (e < NE) {
        int r = row[e], c = col[e];
        int pos = ptr[r] + atomicAdd(&fill[r], 1);
        ecol[pos] = c;
        env[pos] = -dinv[r] * w[e] * dinv[c];   // -(2/lambda_max)*dinv*w*dinv, lambda_max=2
    }
}

// ---- CSR SpMV: one 64-lane wave per row, lane = feature, plain store ----
__global__ __launch_bounds__(256) void spmv_csr_kernel(const int* __restrict__ ptr,
                                                       const int* __restrict__ ecol,
                                                       const float* __restrict__ env,
                                                       const float* __restrict__ h,
                                                       float* __restrict__ y) {
    int g = blockIdx.x * blockDim.x + threadIdx.x;
    int r = g >> 6, lane = g & 63;
    if (r >= NN) return;
    int s = ptr[r], t = ptr[r + 1];
    float a0 = 0.f, a1 = 0.f;
    int i = s;
    for (; i + 1 < t; i += 2) {
        int c0 = ecol[i], c1 = ecol[i + 1];
        float w0 = env[i], w1 = env[i + 1];
        a0 = fmaf(w0, h[c0 * DH + lane], a0);
        a1 = fmaf(w1, h[c1 * DH + lane], a1);
    }
    if (i < t) a0 = fmaf(env[i], h[ecol[i] * DH + lane], a0);
    y[r * DH + lane] = a0 + a1;
}

// ---- fused: out = relu(Tx0@W[0] + Tx1@W[1] + (2*y2 - Tx0)@W[2] + b) ----
template<int DOUT, int NPB>
__global__ __launch_bounds__(DOUT * NPB)
void gemm_kernel(const float* __restrict__ tx0g, const float* __restrict__ y1g,
                 const float* __restrict__ y2g, const float* __restrict__ Wg,
                 const float* __restrict__ bg, float* __restrict__ outg) {
    __shared__ float Ws[3 * DH * DOUT];
    __shared__ float tx[NPB][3][DH];
    const int nthr = DOUT * NPB;
    int tid = threadIdx.x;
    for (int i = tid; i < 3 * DH * DOUT; i += nthr) Ws[i] = Wg[i];
    int ln = tid / DOUT;
    int o = tid - ln * DOUT;
    float bias = bg[o];
    for (int base = blockIdx.x * NPB; base < NN; base += gridDim.x * NPB) {
        __syncthreads();
        for (int i = tid; i < NPB * DH; i += nthr) {
            int l = i >> 6, f = i & 63;
            int n = base + l;
            float a0 = 0.f, a1 = 0.f, a2 = 0.f;
            if (n < NN) {
                a0 = tx0g[n * DH + f];
                a1 = y1g[n * DH + f];
                a2 = 2.f * y2g[n * DH + f] - a0;  // Tx2 = 2*L(Tx1) - Tx0
            }
            tx[l][0][f] = a0;
            tx[l][1][f] = a1;
            tx[l][2][f] = a2;
        }
        __syncthreads();
        int n = base + ln;
        if (n < NN) {
            float acc = bias;
            #pragma unroll
            for (int i = 0; i < DH; ++i) {
                acc = fmaf(tx[ln][0][i], Ws[i * DOUT + o], acc);
                acc = fmaf(tx[ln][1][i], Ws[(DH + i) * DOUT + o], acc);
                acc = fmaf(tx[ln][2][i], Ws[(2 * DH + i) * DOUT + o], acc);
            }
            acc = fmaxf(acc, 0.f);
            outg[n * DOUT + o] = acc;
        }
    }
}

// ---- in-place log_softmax over last dim (40), one 64-lane group per node ----
__global__ void lsm_kernel(float* __restrict__ out) {
    int g = blockIdx.x * blockDim.x + threadIdx.x;
    int node = g >> 6, lane = g & 63;
    if (node >= NN) return;
    float v = lane < DO ? out[node * DO + lane] : -INFINITY;
    float m = v;
    #pragma unroll
    for (int off = 32; off > 0; off >>= 1) m = fmaxf(m, __shfl_xor(m, off));
    float ex = lane < DO ? __expf(v - m) : 0.f;
    float s = ex;
    #pragma unroll
    for (int off = 32; off > 0; off >>= 1) s += __shfl_xor(s, off);
    if (lane < DO) out[node * DO + lane] = v - m - __logf(s);
}

extern "C" void kernel_launch(void* const* d_in, const int* in_sizes, int n_in,
                              void* d_out, int out_size, void* d_ws, size_t ws_size,
                              hipStream_t stream) {
    const float* x  = (const float*)d_in[0];
    const int*   ei = (const int*)d_in[1];   // [2][E] int32
    const float* ea = (const float*)d_in[2];
    const float* W0 = (const float*)d_in[3];
    const float* b0 = (const float*)d_in[4];
    const float* W1 = (const float*)d_in[5];
    const float* b1 = (const float*)d_in[6];
    const float* W2 = (const float*)d_in[7];
    const float* b2 = (const float*)d_in[8];
    float* out = (float*)d_out;

    const int* row = ei;        // edge_index[0]
    const int* col = ei + NE;   // edge_index[1]

    char* p = (char*)d_ws;
    float* deg  = (float*)p; p += (size_t)NN * 4;          // becomes dinv
    int*   cnt  = (int*)p;   p += (size_t)NN * 4;          // reused as fill
    int*   excl = (int*)p;   p += (size_t)NN * 4;
    int*   bsum = (int*)p;   p += (size_t)256 * 4;
    int*   ptr  = (int*)p;   p += (size_t)(NN + 1) * 4;
    int*   ecol = (int*)p;   p += (size_t)NE * 4;
    float* env  = (float*)p; p += (size_t)NE * 4;
    float* y1   = (float*)p; p += (size_t)NN * DH * 4;
    float* y2   = (float*)p; p += (size_t)NN * DH * 4;
    float* hA   = (float*)p; p += (size_t)NN * DH * 4;
    float* hB   = (float*)p; p += (size_t)NN * DH * 4;

    // ---- CSR build (once; serves all 6 SpMVs) ----
    hipMemsetAsync(deg, 0, (size_t)NN * 4, stream);
    hipMemsetAsync(cnt, 0, (size_t)NN * 4, stream);
    deg_hist_kernel<<<(NE + 255) / 256, 256, 0, stream>>>(row, ea, deg, cnt);
    dinv_kernel<<<(NN + 255) / 256, 256, 0, stream>>>(deg);
    scan_block_kernel<<<SCAN_NB, SCAN_BS, 0, stream>>>(cnt, excl, bsum);
    scan_bsum_kernel<<<1, 64, 0, stream>>>(bsum);
    ptr_kernel<<<(NN + 255) / 256, 256, 0, stream>>>(excl, bsum, ptr);
    hipMemsetAsync(cnt, 0, (size_t)NN * 4, stream);  // fill counters
    scatter_kernel<<<(NE + 255) / 256, 256, 0, stream>>>(row, col, ea, deg, ptr, cnt, ecol, env);

    const int SPMV_GRID = (NN * 64 + 255) / 256;   // one wave per row

    // ---- layer 0 (h = x) ----
    spmv_csr_kernel<<<SPMV_GRID, 256, 0, stream>>>(ptr, ecol, env, x, y1);
    spmv_csr_kernel<<<SPMV_GRID, 256, 0, stream>>>(ptr, ecol, env, y1, y2);
    gemm_kernel<DH, 4><<<2500, DH * 4, 0, stream>>>(x, y1, y2, W0, b0, hA);

    // ---- layer 1 (h = hA) ----
    spmv_csr_kernel<<<SPMV_GRID, 256, 0, stream>>>(ptr, ecol, env, hA, y1);
    spmv_csr_kernel<<<SPMV_GRID, 256, 0, stream>>>(ptr, ecol, env, y1, y2);
    gemm_kernel<DH, 4><<<2500, DH * 4, 0, stream>>>(hA, y1, y2, W1, b1, hB);

    // ---- layer 2 (h = hB) -> logits into d_out ----
    spmv_csr_kernel<<<SPMV_GRID, 256, 0, stream>>>(ptr, ecol, env, hB, y1);
    spmv_csr_kernel<<<SPMV_GRID, 256, 0, stream>>>(ptr, ecol, env, y1, y2);
    gemm_kernel<DO, 8><<<2500, DO * 8, 0, stream>>>(hB, y1, y2, W2, b2, out);

    // ---- log_softmax in place on d_out ----
    lsm_kernel<<<(NN * 64 + 255) / 256, 256, 0, stream>>>(out);
}

// Round 3
// 968.589 us; speedup vs baseline: 2.5462x; 1.2316x over previous
//
#include <hip/hip_runtime.h>
#include <math.h>

#define NN 100000
#define NE 1600000
#define DH 64
#define DO 40
#define SCAN_BS 1024
#define SCAN_NB ((NN + SCAN_BS - 1) / SCAN_BS)   // 98

// ---- packed histogram: pk[row] += (1<<40) | fixpoint24(w) ----
__global__ void deg_hist_kernel(const int* __restrict__ row, const float* __restrict__ w,
                                unsigned long long* __restrict__ pk) {
    int e = blockIdx.x * blockDim.x + threadIdx.x;
    if (e < NE) {
        unsigned long long v = (1ull << 40) |
            (unsigned long long)(unsigned)(w[e] * 16777216.0f + 0.5f);
        atomicAdd(&pk[row[e]], v);
    }
}

// ---- unpack: dinv = deg^-0.5 (0 if deg==0), cnt = edge count ----
__global__ void dinv_kernel(const unsigned long long* __restrict__ pk,
                            float* __restrict__ dinv, int* __restrict__ cnt) {
    int i = blockIdx.x * blockDim.x + threadIdx.x;
    if (i < NN) {
        unsigned long long v = pk[i];
        float d = (float)(v & ((1ull << 40) - 1)) * (1.0f / 16777216.0f);
        dinv[i] = d > 0.f ? 1.0f / sqrtf(d) : 0.f;
        cnt[i] = (int)(v >> 40);
    }
}

// ---- block-level exclusive scan of cnt ----
__global__ __launch_bounds__(SCAN_BS) void scan_block_kernel(const int* __restrict__ cnt,
                                                             int* __restrict__ excl,
                                                             int* __restrict__ bsum) {
    __shared__ int tmp[SCAN_BS];
    int tid = threadIdx.x;
    int i = blockIdx.x * SCAN_BS + tid;
    int v = (i < NN) ? cnt[i] : 0;
    tmp[tid] = v;
    __syncthreads();
    for (int off = 1; off < SCAN_BS; off <<= 1) {
        int t = (tid >= off) ? tmp[tid - off] : 0;
        __syncthreads();
        tmp[tid] += t;
        __syncthreads();
    }
    if (i < NN) excl[i] = tmp[tid] - v;
    if (tid == SCAN_BS - 1) bsum[blockIdx.x] = tmp[tid];
}

__global__ void scan_bsum_kernel(int* __restrict__ bsum) {
    if (threadIdx.x == 0 && blockIdx.x == 0) {
        int run = 0;
        for (int j = 0; j < SCAN_NB; ++j) { int t = bsum[j]; bsum[j] = run; run += t; }
    }
}

__global__ void ptr_kernel(const int* __restrict__ excl, const int* __restrict__ bsum,
                           int* __restrict__ ptr) {
    int i = blockIdx.x * blockDim.x + threadIdx.x;
    if (i < NN) ptr[i] = excl[i] + bsum[i >> 10];
    if (i == 0) ptr[NN] = NE;
}

// ---- scatter edges into CSR order; fold in norm ----
__global__ void scatter_kernel(const int* __restrict__ row, const int* __restrict__ col,
                               const float* __restrict__ w, const float* __restrict__ dinv,
                               const int* __restrict__ ptr, int* __restrict__ fill,
                               int* __restrict__ ecol, float* __restrict__ env) {
    int e = blockIdx.x * blockDim.x + threadIdx.x;
    if (e < NE) {
        int r = row[e], c = col[e];
        int pos = ptr[r] + atomicAdd(&fill[r], 1);
        ecol[pos] = c;
        env[pos] = -dinv[r] * w[e] * dinv[c];   // lambda_max = 2
    }
}

// ---- CSR SpMV: one 64-lane wave per row, lane = feature ----
__global__ __launch_bounds__(256) void spmv_csr_kernel(const int* __restrict__ ptr,
                                                       const int* __restrict__ ecol,
                                                       const float* __restrict__ env,
                                                       const float* __restrict__ h,
                                                       float* __restrict__ y) {
    int g = blockIdx.x * blockDim.x + threadIdx.x;
    int r = g >> 6, lane = g & 63;
    if (r >= NN) return;
    int s = ptr[r], t = ptr[r + 1];
    float a0 = 0.f, a1 = 0.f;
    int i = s;
    for (; i + 1 < t; i += 2) {
        int c0 = ecol[i], c1 = ecol[i + 1];
        float w0 = env[i], w1 = env[i + 1];
        a0 = fmaf(w0, h[c0 * DH + lane], a0);
        a1 = fmaf(w1, h[c1 * DH + lane], a1);
    }
    if (i < t) a0 = fmaf(env[i], h[ecol[i] * DH + lane], a0);
    y[r * DH + lane] = a0 + a1;
}

// ---- fused 3-matrix GEMM, register-tiled 4 nodes x 2 outputs per thread ----
// out[n][o] = relu( sum_j tx_j[n] @ W[j] + b ), tx2 = 2*y2 - tx0 folded at staging.
// Block: 32 nodes, 256 threads (oT = tid&31 -> outputs 2oT,2oT+1; nT = tid>>5 -> 4 nodes).
// SW = actual output width (64 or 40); W padded to 64-wide in LDS when SW==40.
template<int SW>
__global__ __launch_bounds__(256)
void gemm3_kernel(const float* __restrict__ tx0g, const float* __restrict__ y1g,
                  const float* __restrict__ y2g, const float* __restrict__ Wg,
                  const float* __restrict__ bg, float* __restrict__ outg) {
    __shared__ float tx[3 * 32 * DH];   // [j][n][i]
    __shared__ float Ws[DH * 64];       // [i][o] one j at a time
    int tid = threadIdx.x;
    int oT = tid & 31, nT = tid >> 5;
    int base = blockIdx.x * 32;

    // stage tx (all three j) as float4
    {
        float4* t4 = (float4*)tx;
        for (int q = tid; q < 3 * 32 * 16; q += 256) {
            int jj = q >> 9, rem = q & 511, n = rem >> 4, i4 = rem & 15;
            int node = base + n;
            float4 v = make_float4(0.f, 0.f, 0.f, 0.f);
            if (node < NN) {
                if (jj == 0) v = ((const float4*)tx0g)[node * 16 + i4];
                else if (jj == 1) v = ((const float4*)y1g)[node * 16 + i4];
                else {
                    float4 a = ((const float4*)y2g)[node * 16 + i4];
                    float4 b = ((const float4*)tx0g)[node * 16 + i4];
                    v = make_float4(2.f * a.x - b.x, 2.f * a.y - b.y,
                                    2.f * a.z - b.z, 2.f * a.w - b.w);
                }
            }
            t4[q] = v;
        }
    }

    float acc[4][2];
    #pragma unroll
    for (int n = 0; n < 4; ++n) { acc[n][0] = 0.f; acc[n][1] = 0.f; }

    for (int j = 0; j < 3; ++j) {
        __syncthreads();   // tx ready (j=0) / previous compute done (j>0)
        if (SW == 64) {
            float4* w4 = (float4*)Ws;
            const float4* g4 = (const float4*)(Wg + j * DH * 64);
            for (int q = tid; q < DH * 16; q += 256) w4[q] = g4[q];
        } else {
            const float* gj = Wg + j * DH * SW;
            for (int q = tid; q < DH * 64; q += 256) {
                int i = q >> 6, o = q & 63;
                Ws[q] = (o < SW) ? gj[i * SW + o] : 0.f;
            }
        }
        __syncthreads();
        const float4* txj = (const float4*)(tx + j * 32 * DH + nT * 4 * DH);
        #pragma unroll 4
        for (int i4 = 0; i4 < 16; ++i4) {
            float4 f0 = txj[i4], f1 = txj[16 + i4], f2 = txj[32 + i4], f3 = txj[48 + i4];
            float a[4][4] = {{f0.x, f0.y, f0.z, f0.w}, {f1.x, f1.y, f1.z, f1.w},
                             {f2.x, f2.y, f2.z, f2.w}, {f3.x, f3.y, f3.z, f3.w}};
            const float2* w2 = (const float2*)(Ws + i4 * 4 * 64) + oT;
            #pragma unroll
            for (int t = 0; t < 4; ++t) {
                float2 w = w2[t * 32];
                #pragma unroll
                for (int n = 0; n < 4; ++n) {
                    acc[n][0] = fmaf(a[n][t], w.x, acc[n][0]);
                    acc[n][1] = fmaf(a[n][t], w.y, acc[n][1]);
                }
            }
        }
    }

    int o0 = oT * 2;
    if (o0 < SW) {
        float b0 = bg[o0], b1 = bg[o0 + 1];
        #pragma unroll
        for (int n = 0; n < 4; ++n) {
            int node = base + nT * 4 + n;
            if (node < NN) {
                float v0 = fmaxf(acc[n][0] + b0, 0.f);
                float v1 = fmaxf(acc[n][1] + b1, 0.f);
                *(float2*)(outg + (size_t)node * SW + o0) = make_float2(v0, v1);
            }
        }
    }
}

// ---- in-place log_softmax over last dim (40) ----
__global__ void lsm_kernel(float* __restrict__ out) {
    int g = blockIdx.x * blockDim.x + threadIdx.x;
    int node = g >> 6, lane = g & 63;
    if (node >= NN) return;
    float v = lane < DO ? out[node * DO + lane] : -INFINITY;
    float m = v;
    #pragma unroll
    for (int off = 32; off > 0; off >>= 1) m = fmaxf(m, __shfl_xor(m, off));
    float ex = lane < DO ? __expf(v - m) : 0.f;
    float s = ex;
    #pragma unroll
    for (int off = 32; off > 0; off >>= 1) s += __shfl_xor(s, off);
    if (lane < DO) out[node * DO + lane] = v - m - __logf(s);
}

extern "C" void kernel_launch(void* const* d_in, const int* in_sizes, int n_in,
                              void* d_out, int out_size, void* d_ws, size_t ws_size,
                              hipStream_t stream) {
    const float* x  = (const float*)d_in[0];
    const int*   ei = (const int*)d_in[1];
    const float* ea = (const float*)d_in[2];
    const float* W0 = (const float*)d_in[3];
    const float* b0 = (const float*)d_in[4];
    const float* W1 = (const float*)d_in[5];
    const float* b1 = (const float*)d_in[6];
    const float* W2 = (const float*)d_in[7];
    const float* b2 = (const float*)d_in[8];
    float* out = (float*)d_out;

    const int* row = ei;
    const int* col = ei + NE;

    const size_t HBYTES = (size_t)NN * DH * 4;
    char* p = (char*)d_ws;
    int*   ptr  = (int*)p;   p += (size_t)(NN + 4) * 4;
    int*   ecol = (int*)p;   p += (size_t)NE * 4;
    float* env  = (float*)p; p += (size_t)NE * 4;
    float* y1   = (float*)p; p += HBYTES;
    float* y2   = (float*)p; p += HBYTES;
    float* hA   = (float*)p; p += HBYTES;
    float* hB   = (float*)p;                    // also hosts CSR-build transients
    // transients inside hB region (dead before hB is first written at layer-1 gemm)
    char* q = (char*)hB;
    unsigned long long* pk = (unsigned long long*)q; q += (size_t)NN * 8;
    float* dinv = (float*)q; q += (size_t)NN * 4;
    int*   cnt  = (int*)q;   q += (size_t)NN * 4;   // scan input, then reused as fill
    int*   excl = (int*)q;   q += (size_t)NN * 4;
    int*   bsum = (int*)q;   q += (size_t)256 * 4;

    // ---- CSR build ----
    hipMemsetAsync(pk, 0, (size_t)NN * 8, stream);
    deg_hist_kernel<<<(NE + 255) / 256, 256, 0, stream>>>(row, ea, pk);
    dinv_kernel<<<(NN + 255) / 256, 256, 0, stream>>>(pk, dinv, cnt);
    scan_block_kernel<<<SCAN_NB, SCAN_BS, 0, stream>>>(cnt, excl, bsum);
    scan_bsum_kernel<<<1, 64, 0, stream>>>(bsum);
    ptr_kernel<<<(NN + 255) / 256, 256, 0, stream>>>(excl, bsum, ptr);
    hipMemsetAsync(cnt, 0, (size_t)NN * 4, stream);
    scatter_kernel<<<(NE + 255) / 256, 256, 0, stream>>>(row, col, ea, dinv, ptr, cnt, ecol, env);

    const int SPMV_GRID = (NN * 64 + 255) / 256;
    const int GEMM_GRID = (NN + 31) / 32;

    // ---- layer 0 (h = x) ----
    spmv_csr_kernel<<<SPMV_GRID, 256, 0, stream>>>(ptr, ecol, env, x, y1);
    spmv_csr_kernel<<<SPMV_GRID, 256, 0, stream>>>(ptr, ecol, env, y1, y2);
    gemm3_kernel<64><<<GEMM_GRID, 256, 0, stream>>>(x, y1, y2, W0, b0, hA);

    // ---- layer 1 (h = hA) ----
    spmv_csr_kernel<<<SPMV_GRID, 256, 0, stream>>>(ptr, ecol, env, hA, y1);
    spmv_csr_kernel<<<SPMV_GRID, 256, 0, stream>>>(ptr, ecol, env, y1, y2);
    gemm3_kernel<64><<<GEMM_GRID, 256, 0, stream>>>(hA, y1, y2, W1, b1, hB);

    // ---- layer 2 (h = hB) -> logits into d_out ----
    spmv_csr_kernel<<<SPMV_GRID, 256, 0, stream>>>(ptr, ecol, env, hB, y1);
    spmv_csr_kernel<<<SPMV_GRID, 256, 0, stream>>>(ptr, ecol, env, y1, y2);
    gemm3_kernel<40><<<GEMM_GRID, 256, 0, stream>>>(hB, y1, y2, W2, b2, out);

    // ---- log_softmax in place ----
    lsm_kernel<<<(NN * 64 + 255) / 256, 256, 0, stream>>>(out);
}

// Round 4
// 829.197 us; speedup vs baseline: 2.9742x; 1.1681x over previous
//
#include <hip/hip_runtime.h>
#include <math.h>

#define NN 100000
#define NE 1600000
#define DH 64
#define DO 40
#define SCAN_BS 1024
#define SCAN_NB ((NN + SCAN_BS - 1) / SCAN_BS)   // 98

// ---- packed histogram: pk[row] += (1<<40) | fixpoint24(w) ----
__global__ void deg_hist_kernel(const int* __restrict__ row, const float* __restrict__ w,
                                unsigned long long* __restrict__ pk) {
    int e = blockIdx.x * blockDim.x + threadIdx.x;
    if (e < NE) {
        unsigned long long v = (1ull << 40) |
            (unsigned long long)(unsigned)(w[e] * 16777216.0f + 0.5f);
        atomicAdd(&pk[row[e]], v);
    }
}

// ---- unpack: dinv = deg^-0.5 (0 if deg==0), cnt = edge count ----
__global__ void dinv_kernel(const unsigned long long* __restrict__ pk,
                            float* __restrict__ dinv, int* __restrict__ cnt) {
    int i = blockIdx.x * blockDim.x + threadIdx.x;
    if (i < NN) {
        unsigned long long v = pk[i];
        float d = (float)(v & ((1ull << 40) - 1)) * (1.0f / 16777216.0f);
        dinv[i] = d > 0.f ? 1.0f / sqrtf(d) : 0.f;
        cnt[i] = (int)(v >> 40);
    }
}

// ---- block-level exclusive scan of cnt ----
__global__ __launch_bounds__(SCAN_BS) void scan_block_kernel(const int* __restrict__ cnt,
                                                             int* __restrict__ excl,
                                                             int* __restrict__ bsum) {
    __shared__ int tmp[SCAN_BS];
    int tid = threadIdx.x;
    int i = blockIdx.x * SCAN_BS + tid;
    int v = (i < NN) ? cnt[i] : 0;
    tmp[tid] = v;
    __syncthreads();
    for (int off = 1; off < SCAN_BS; off <<= 1) {
        int t = (tid >= off) ? tmp[tid - off] : 0;
        __syncthreads();
        tmp[tid] += t;
        __syncthreads();
    }
    if (i < NN) excl[i] = tmp[tid] - v;
    if (tid == SCAN_BS - 1) bsum[blockIdx.x] = tmp[tid];
}

__global__ void scan_bsum_kernel(int* __restrict__ bsum) {
    if (threadIdx.x == 0 && blockIdx.x == 0) {
        int run = 0;
        for (int j = 0; j < SCAN_NB; ++j) { int t = bsum[j]; bsum[j] = run; run += t; }
    }
}

__global__ void ptr_kernel(const int* __restrict__ excl, const int* __restrict__ bsum,
                           int* __restrict__ ptr) {
    int i = blockIdx.x * blockDim.x + threadIdx.x;
    if (i < NN) ptr[i] = excl[i] + bsum[i >> 10];
    if (i == 0) ptr[NN] = NE;
}

// ---- scatter edges into CSR order; packed (col, norm) single 8B store ----
__global__ void scatter_kernel(const int* __restrict__ row, const int* __restrict__ col,
                               const float* __restrict__ w, const float* __restrict__ dinv,
                               const int* __restrict__ ptr, int* __restrict__ fill,
                               int2* __restrict__ epack) {
    int e = blockIdx.x * blockDim.x + threadIdx.x;
    if (e < NE) {
        int r = row[e], c = col[e];
        int pos = ptr[r] + atomicAdd(&fill[r], 1);
        float nv = -dinv[r] * w[e] * dinv[c];   // lambda_max = 2
        epack[pos] = make_int2(c, __float_as_int(nv));
    }
}

// ---- CSR SpMV: one wave per row, lane = feature. Metadata loaded coalesced
// (lane l -> edge s+l) and broadcast via shfl; gathers unrolled x4 for MLP. ----
__global__ __launch_bounds__(256) void spmv_csr_kernel(const int* __restrict__ ptr,
                                                       const int2* __restrict__ epack,
                                                       const float* __restrict__ h,
                                                       float* __restrict__ y) {
    int g = blockIdx.x * blockDim.x + threadIdx.x;
    int r = g >> 6, lane = g & 63;
    if (r >= NN) return;
    int s = ptr[r], t = ptr[r + 1];
    float a0 = 0.f, a1 = 0.f, a2 = 0.f, a3 = 0.f;
    for (int base = s; base < t; base += 64) {
        int n = t - base; if (n > 64) n = 64;
        int2 ep = make_int2(0, 0);
        if (lane < n) ep = epack[base + lane];
        int i = 0;
        for (; i + 4 <= n; i += 4) {
            int   c0 = __shfl(ep.x, i);     float w0 = __int_as_float(__shfl(ep.y, i));
            int   c1 = __shfl(ep.x, i + 1); float w1 = __int_as_float(__shfl(ep.y, i + 1));
            int   c2 = __shfl(ep.x, i + 2); float w2 = __int_as_float(__shfl(ep.y, i + 2));
            int   c3 = __shfl(ep.x, i + 3); float w3 = __int_as_float(__shfl(ep.y, i + 3));
            float h0 = h[(size_t)c0 * DH + lane];
            float h1 = h[(size_t)c1 * DH + lane];
            float h2 = h[(size_t)c2 * DH + lane];
            float h3 = h[(size_t)c3 * DH + lane];
            a0 = fmaf(w0, h0, a0);
            a1 = fmaf(w1, h1, a1);
            a2 = fmaf(w2, h2, a2);
            a3 = fmaf(w3, h3, a3);
        }
        for (; i < n; ++i) {
            int c = __shfl(ep.x, i); float w = __int_as_float(__shfl(ep.y, i));
            a0 = fmaf(w, h[(size_t)c * DH + lane], a0);
        }
    }
    y[(size_t)r * DH + lane] = (a0 + a1) + (a2 + a3);
}

// ---- fused 3-matrix GEMM, register-tiled 4 nodes x 2 outputs per thread ----
template<int SW>
__global__ __launch_bounds__(256)
void gemm3_kernel(const float* __restrict__ tx0g, const float* __restrict__ y1g,
                  const float* __restrict__ y2g, const float* __restrict__ Wg,
                  const float* __restrict__ bg, float* __restrict__ outg) {
    __shared__ float tx[3 * 32 * DH];   // [j][n][i]
    __shared__ float Ws[DH * 64];       // [i][o] one j at a time
    int tid = threadIdx.x;
    int oT = tid & 31, nT = tid >> 5;
    int base = blockIdx.x * 32;

    {
        float4* t4 = (float4*)tx;
        for (int q = tid; q < 3 * 32 * 16; q += 256) {
            int jj = q >> 9, rem = q & 511, n = rem >> 4, i4 = rem & 15;
            int node = base + n;
            float4 v = make_float4(0.f, 0.f, 0.f, 0.f);
            if (node < NN) {
                if (jj == 0) v = ((const float4*)tx0g)[node * 16 + i4];
                else if (jj == 1) v = ((const float4*)y1g)[node * 16 + i4];
                else {
                    float4 a = ((const float4*)y2g)[node * 16 + i4];
                    float4 b = ((const float4*)tx0g)[node * 16 + i4];
                    v = make_float4(2.f * a.x - b.x, 2.f * a.y - b.y,
                                    2.f * a.z - b.z, 2.f * a.w - b.w);
                }
            }
            t4[q] = v;
        }
    }

    float acc[4][2];
    #pragma unroll
    for (int n = 0; n < 4; ++n) { acc[n][0] = 0.f; acc[n][1] = 0.f; }

    for (int j = 0; j < 3; ++j) {
        __syncthreads();
        if (SW == 64) {
            float4* w4 = (float4*)Ws;
            const float4* g4 = (const float4*)(Wg + j * DH * 64);
            for (int q = tid; q < DH * 16; q += 256) w4[q] = g4[q];
        } else {
            const float* gj = Wg + j * DH * SW;
            for (int q = tid; q < DH * 64; q += 256) {
                int i = q >> 6, o = q & 63;
                Ws[q] = (o < SW) ? gj[i * SW + o] : 0.f;
            }
        }
        __syncthreads();
        const float4* txj = (const float4*)(tx + j * 32 * DH + nT * 4 * DH);
        #pragma unroll 4
        for (int i4 = 0; i4 < 16; ++i4) {
            float4 f0 = txj[i4], f1 = txj[16 + i4], f2 = txj[32 + i4], f3 = txj[48 + i4];
            float a[4][4] = {{f0.x, f0.y, f0.z, f0.w}, {f1.x, f1.y, f1.z, f1.w},
                             {f2.x, f2.y, f2.z, f2.w}, {f3.x, f3.y, f3.z, f3.w}};
            const float2* w2 = (const float2*)(Ws + i4 * 4 * 64) + oT;
            #pragma unroll
            for (int t = 0; t < 4; ++t) {
                float2 w = w2[t * 32];
                #pragma unroll
                for (int n = 0; n < 4; ++n) {
                    acc[n][0] = fmaf(a[n][t], w.x, acc[n][0]);
                    acc[n][1] = fmaf(a[n][t], w.y, acc[n][1]);
                }
            }
        }
    }

    int o0 = oT * 2;
    if (o0 < SW) {
        float b0 = bg[o0], b1 = bg[o0 + 1];
        #pragma unroll
        for (int n = 0; n < 4; ++n) {
            int node = base + nT * 4 + n;
            if (node < NN) {
                float v0 = fmaxf(acc[n][0] + b0, 0.f);
                float v1 = fmaxf(acc[n][1] + b1, 0.f);
                *(float2*)(outg + (size_t)node * SW + o0) = make_float2(v0, v1);
            }
        }
    }
}

// ---- in-place log_softmax over last dim (40) ----
__global__ void lsm_kernel(float* __restrict__ out) {
    int g = blockIdx.x * blockDim.x + threadIdx.x;
    int node = g >> 6, lane = g & 63;
    if (node >= NN) return;
    float v = lane < DO ? out[node * DO + lane] : -INFINITY;
    float m = v;
    #pragma unroll
    for (int off = 32; off > 0; off >>= 1) m = fmaxf(m, __shfl_xor(m, off));
    float ex = lane < DO ? __expf(v - m) : 0.f;
    float s = ex;
    #pragma unroll
    for (int off = 32; off > 0; off >>= 1) s += __shfl_xor(s, off);
    if (lane < DO) out[node * DO + lane] = v - m - __logf(s);
}

extern "C" void kernel_launch(void* const* d_in, const int* in_sizes, int n_in,
                              void* d_out, int out_size, void* d_ws, size_t ws_size,
                              hipStream_t stream) {
    const float* x  = (const float*)d_in[0];
    const int*   ei = (const int*)d_in[1];
    const float* ea = (const float*)d_in[2];
    const float* W0 = (const float*)d_in[3];
    const float* b0 = (const float*)d_in[4];
    const float* W1 = (const float*)d_in[5];
    const float* b1 = (const float*)d_in[6];
    const float* W2 = (const float*)d_in[7];
    const float* b2 = (const float*)d_in[8];
    float* out = (float*)d_out;

    const int* row = ei;
    const int* col = ei + NE;

    const size_t HBYTES = (size_t)NN * DH * 4;
    char* p = (char*)d_ws;
    int*   ptr   = (int*)p;  p += (size_t)(NN + 4) * 4;
    int2*  epack = (int2*)p; p += (size_t)NE * 8;
    float* y1    = (float*)p; p += HBYTES;
    float* y2    = (float*)p; p += HBYTES;
    float* hA    = (float*)p; p += HBYTES;
    float* hB    = (float*)p;                   // also hosts CSR-build transients
    char* q = (char*)hB;
    unsigned long long* pk = (unsigned long long*)q; q += (size_t)NN * 8;
    float* dinv = (float*)q; q += (size_t)NN * 4;
    int*   cnt  = (int*)q;   q += (size_t)NN * 4;   // scan input, then fill counters
    int*   excl = (int*)q;   q += (size_t)NN * 4;
    int*   bsum = (int*)q;   q += (size_t)256 * 4;

    // ---- CSR build ----
    hipMemsetAsync(pk, 0, (size_t)NN * 8, stream);
    deg_hist_kernel<<<(NE + 255) / 256, 256, 0, stream>>>(row, ea, pk);
    dinv_kernel<<<(NN + 255) / 256, 256, 0, stream>>>(pk, dinv, cnt);
    scan_block_kernel<<<SCAN_NB, SCAN_BS, 0, stream>>>(cnt, excl, bsum);
    scan_bsum_kernel<<<1, 64, 0, stream>>>(bsum);
    ptr_kernel<<<(NN + 255) / 256, 256, 0, stream>>>(excl, bsum, ptr);
    hipMemsetAsync(cnt, 0, (size_t)NN * 4, stream);
    scatter_kernel<<<(NE + 255) / 256, 256, 0, stream>>>(row, col, ea, dinv, ptr, cnt, epack);

    const int SPMV_GRID = (NN * 64 + 255) / 256;
    const int GEMM_GRID = (NN + 31) / 32;

    // ---- layer 0 (h = x) ----
    spmv_csr_kernel<<<SPMV_GRID, 256, 0, stream>>>(ptr, epack, x, y1);
    spmv_csr_kernel<<<SPMV_GRID, 256, 0, stream>>>(ptr, epack, y1, y2);
    gemm3_kernel<64><<<GEMM_GRID, 256, 0, stream>>>(x, y1, y2, W0, b0, hA);

    // ---- layer 1 (h = hA) ----
    spmv_csr_kernel<<<SPMV_GRID, 256, 0, stream>>>(ptr, epack, hA, y1);
    spmv_csr_kernel<<<SPMV_GRID, 256, 0, stream>>>(ptr, epack, y1, y2);
    gemm3_kernel<64><<<GEMM_GRID, 256, 0, stream>>>(hA, y1, y2, W1, b1, hB);

    // ---- layer 2 (h = hB) -> logits into d_out ----
    spmv_csr_kernel<<<SPMV_GRID, 256, 0, stream>>>(ptr, epack, hB, y1);
    spmv_csr_kernel<<<SPMV_GRID, 256, 0, stream>>>(ptr, epack, y1, y2);
    gemm3_kernel<40><<<GEMM_GRID, 256, 0, stream>>>(hB, y1, y2, W2, b2, out);

    // ---- log_softmax in place ----
    lsm_kernel<<<(NN * 64 + 255) / 256, 256, 0, stream>>>(out);
}

// Round 5
// 735.339 us; speedup vs baseline: 3.3538x; 1.1276x over previous
//
#include <hip/hip_runtime.h>
#include <math.h>

#define NN 100000
#define NE 1600000
#define DH 64
#define DO 40
#define SCAN_BS 1024
#define SCAN_NB ((NN + SCAN_BS - 1) / SCAN_BS)   // 98

typedef __attribute__((ext_vector_type(8))) short bf16x8;
typedef __attribute__((ext_vector_type(4))) float f32x4;

__device__ inline unsigned short f2bf(float f) {   // fp32 -> bf16 RNE
    unsigned u = __float_as_uint(f);
    u = (u + 0x7FFF + ((u >> 16) & 1)) >> 16;
    return (unsigned short)u;
}

// ---- packed histogram: pk[row] += (1<<40) | fixpoint24(w) ----
__global__ void deg_hist_kernel(const int* __restrict__ row, const float* __restrict__ w,
                                unsigned long long* __restrict__ pk) {
    int e = blockIdx.x * blockDim.x + threadIdx.x;
    if (e < NE) {
        unsigned long long v = (1ull << 40) |
            (unsigned long long)(unsigned)(w[e] * 16777216.0f + 0.5f);
        atomicAdd(&pk[row[e]], v);
    }
}

// ---- unpack: dinv = deg^-0.5 (0 if deg==0), cnt = edge count ----
__global__ void dinv_kernel(const unsigned long long* __restrict__ pk,
                            float* __restrict__ dinv, int* __restrict__ cnt) {
    int i = blockIdx.x * blockDim.x + threadIdx.x;
    if (i < NN) {
        unsigned long long v = pk[i];
        float d = (float)(v & ((1ull << 40) - 1)) * (1.0f / 16777216.0f);
        dinv[i] = d > 0.f ? 1.0f / sqrtf(d) : 0.f;
        cnt[i] = (int)(v >> 40);
    }
}

// ---- block-level exclusive scan of cnt ----
__global__ __launch_bounds__(SCAN_BS) void scan_block_kernel(const int* __restrict__ cnt,
                                                             int* __restrict__ excl,
                                                             int* __restrict__ bsum) {
    __shared__ int tmp[SCAN_BS];
    int tid = threadIdx.x;
    int i = blockIdx.x * SCAN_BS + tid;
    int v = (i < NN) ? cnt[i] : 0;
    tmp[tid] = v;
    __syncthreads();
    for (int off = 1; off < SCAN_BS; off <<= 1) {
        int t = (tid >= off) ? tmp[tid - off] : 0;
        __syncthreads();
        tmp[tid] += t;
        __syncthreads();
    }
    if (i < NN) excl[i] = tmp[tid] - v;
    if (tid == SCAN_BS - 1) bsum[blockIdx.x] = tmp[tid];
}

__global__ void scan_bsum_kernel(int* __restrict__ bsum) {
    if (threadIdx.x == 0 && blockIdx.x == 0) {
        int run = 0;
        for (int j = 0; j < SCAN_NB; ++j) { int t = bsum[j]; bsum[j] = run; run += t; }
    }
}

__global__ void ptr_kernel(const int* __restrict__ excl, const int* __restrict__ bsum,
                           int* __restrict__ ptr) {
    int i = blockIdx.x * blockDim.x + threadIdx.x;
    if (i < NN) ptr[i] = excl[i] + bsum[i >> 10];
    if (i == 0) ptr[NN] = NE;
}

// ---- scatter edges into CSR order; packed (col, norm) single 8B store ----
__global__ void scatter_kernel(const int* __restrict__ row, const int* __restrict__ col,
                               const float* __restrict__ w, const float* __restrict__ dinv,
                               const int* __restrict__ ptr, int* __restrict__ fill,
                               int2* __restrict__ epack) {
    int e = blockIdx.x * blockDim.x + threadIdx.x;
    if (e < NE) {
        int r = row[e], c = col[e];
        int pos = ptr[r] + atomicAdd(&fill[r], 1);
        float nv = -dinv[r] * w[e] * dinv[c];   // lambda_max = 2
        epack[pos] = make_int2(c, __float_as_int(nv));
    }
}

// ---- CSR SpMV: one wave per row, lane = feature, 8-deep gather ILP ----
__global__ __launch_bounds__(256) void spmv_csr_kernel(const int* __restrict__ ptr,
                                                       const int2* __restrict__ epack,
                                                       const float* __restrict__ h,
                                                       float* __restrict__ y) {
    int g = blockIdx.x * blockDim.x + threadIdx.x;
    int r = g >> 6, lane = g & 63;
    if (r >= NN) return;
    int s = ptr[r], t = ptr[r + 1];
    float a0 = 0.f, a1 = 0.f, a2 = 0.f, a3 = 0.f;
    float a4 = 0.f, a5 = 0.f, a6 = 0.f, a7 = 0.f;
    for (int base = s; base < t; base += 64) {
        int n = t - base; if (n > 64) n = 64;
        int2 ep = make_int2(0, 0);
        if (lane < n) ep = epack[base + lane];
        int i = 0;
        for (; i + 8 <= n; i += 8) {
            int   c0 = __shfl(ep.x, i);     float w0 = __int_as_float(__shfl(ep.y, i));
            int   c1 = __shfl(ep.x, i + 1); float w1 = __int_as_float(__shfl(ep.y, i + 1));
            int   c2 = __shfl(ep.x, i + 2); float w2 = __int_as_float(__shfl(ep.y, i + 2));
            int   c3 = __shfl(ep.x, i + 3); float w3 = __int_as_float(__shfl(ep.y, i + 3));
            int   c4 = __shfl(ep.x, i + 4); float w4 = __int_as_float(__shfl(ep.y, i + 4));
            int   c5 = __shfl(ep.x, i + 5); float w5 = __int_as_float(__shfl(ep.y, i + 5));
            int   c6 = __shfl(ep.x, i + 6); float w6 = __int_as_float(__shfl(ep.y, i + 6));
            int   c7 = __shfl(ep.x, i + 7); float w7 = __int_as_float(__shfl(ep.y, i + 7));
            float h0 = h[(size_t)c0 * DH + lane];
            float h1 = h[(size_t)c1 * DH + lane];
            float h2 = h[(size_t)c2 * DH + lane];
            float h3 = h[(size_t)c3 * DH + lane];
            float h4 = h[(size_t)c4 * DH + lane];
            float h5 = h[(size_t)c5 * DH + lane];
            float h6 = h[(size_t)c6 * DH + lane];
            float h7 = h[(size_t)c7 * DH + lane];
            a0 = fmaf(w0, h0, a0); a1 = fmaf(w1, h1, a1);
            a2 = fmaf(w2, h2, a2); a3 = fmaf(w3, h3, a3);
            a4 = fmaf(w4, h4, a4); a5 = fmaf(w5, h5, a5);
            a6 = fmaf(w6, h6, a6); a7 = fmaf(w7, h7, a7);
        }
        for (; i < n; ++i) {
            int c = __shfl(ep.x, i); float w = __int_as_float(__shfl(ep.y, i));
            a0 = fmaf(w, h[(size_t)c * DH + lane], a0);
        }
    }
    y[(size_t)r * DH + lane] = ((a0 + a1) + (a2 + a3)) + ((a4 + a5) + (a6 + a7));
}

// ---- weight prep: Wt[n][192] bf16, k = j*64+kin ----
// j=0: W[0]-W[2]; j=1: W[1]; j=2: 2*W[2]   (folds Tx2 = 2*y2 - Tx0 into weights)
__global__ void wprep_kernel(const float* __restrict__ W, int SW,
                             unsigned short* __restrict__ Wt) {
    int idx = blockIdx.x * 256 + threadIdx.x;
    if (idx >= 64 * 192) return;
    int n = idx / 192, k = idx - n * 192;
    int j = k >> 6, kin = k & 63;
    float v = 0.f;
    if (n < SW) {
        if (j == 0)      v = W[kin * SW + n] - W[2 * 64 * SW + kin * SW + n];
        else if (j == 1) v = W[64 * SW + kin * SW + n];
        else             v = 2.f * W[2 * 64 * SW + kin * SW + n];
    }
    Wt[n * 192 + k] = f2bf(v);
}

// ---- MFMA GEMM: out = relu(h@Wt_j0 + y1@Wt_j1 + y2@Wt_j2 + b) ----
// block = 256 thr = 4 waves; wave w owns 16 nodes (M-tile), NT 16-col tiles.
// A-frag: lane m=l&15 -> node row, k=(l>>4)*8.. (8 fp32 -> bf16).
// B-frag: Wt[n][k] N-major, lane n=l&15, 16B contiguous.
// D: row=(l>>4)*4+r (node), col=l&15 (output).
template<int SW, int NT>
__global__ __launch_bounds__(256)
void gemm3_mfma_kernel(const float* __restrict__ h, const float* __restrict__ y1,
                       const float* __restrict__ y2,
                       const unsigned short* __restrict__ Wt,
                       const float* __restrict__ bg, float* __restrict__ outg) {
    int tid = threadIdx.x;
    int w = tid >> 6, l = tid & 63;
    int m = l & 15, kg = l >> 4;
    int node = blockIdx.x * 64 + w * 16 + m;
    int nclamp = node < NN ? node : NN - 1;

    f32x4 acc[NT];
    #pragma unroll
    for (int t = 0; t < NT; ++t) acc[t] = (f32x4){0.f, 0.f, 0.f, 0.f};

    #pragma unroll
    for (int ks = 0; ks < 6; ++ks) {
        const float* src = (ks < 2) ? h : (ks < 4 ? y1 : y2);
        int kin = (ks & 1) * 32 + kg * 8;
        const float4* pa = (const float4*)(src + (size_t)nclamp * DH + kin);
        float4 v0 = pa[0], v1 = pa[1];
        bf16x8 af;
        af[0] = (short)f2bf(v0.x); af[1] = (short)f2bf(v0.y);
        af[2] = (short)f2bf(v0.z); af[3] = (short)f2bf(v0.w);
        af[4] = (short)f2bf(v1.x); af[5] = (short)f2bf(v1.y);
        af[6] = (short)f2bf(v1.z); af[7] = (short)f2bf(v1.w);
        #pragma unroll
        for (int t = 0; t < NT; ++t) {
            const bf16x8* pb = (const bf16x8*)(Wt + ((size_t)(t * 16 + m) * 192 + ks * 32 + kg * 8));
            acc[t] = __builtin_amdgcn_mfma_f32_16x16x32_bf16(af, *pb, acc[t], 0, 0, 0);
        }
    }

    int orow = blockIdx.x * 64 + w * 16 + kg * 4;   // + r
    #pragma unroll
    for (int t = 0; t < NT; ++t) {
        int oc = t * 16 + m;
        float bias = (oc < SW) ? bg[oc] : 0.f;
        #pragma unroll
        for (int r = 0; r < 4; ++r) {
            int nd = orow + r;
            if (nd < NN && oc < SW)
                outg[(size_t)nd * SW + oc] = fmaxf(acc[t][r] + bias, 0.f);
        }
    }
}

// ---- in-place log_softmax over last dim (40) ----
__global__ void lsm_kernel(float* __restrict__ out) {
    int g = blockIdx.x * blockDim.x + threadIdx.x;
    int node = g >> 6, lane = g & 63;
    if (node >= NN) return;
    float v = lane < DO ? out[node * DO + lane] : -INFINITY;
    float m = v;
    #pragma unroll
    for (int off = 32; off > 0; off >>= 1) m = fmaxf(m, __shfl_xor(m, off));
    float ex = lane < DO ? __expf(v - m) : 0.f;
    float s = ex;
    #pragma unroll
    for (int off = 32; off > 0; off >>= 1) s += __shfl_xor(s, off);
    if (lane < DO) out[node * DO + lane] = v - m - __logf(s);
}

extern "C" void kernel_launch(void* const* d_in, const int* in_sizes, int n_in,
                              void* d_out, int out_size, void* d_ws, size_t ws_size,
                              hipStream_t stream) {
    const float* x  = (const float*)d_in[0];
    const int*   ei = (const int*)d_in[1];
    const float* ea = (const float*)d_in[2];
    const float* W0 = (const float*)d_in[3];
    const float* b0 = (const float*)d_in[4];
    const float* W1 = (const float*)d_in[5];
    const float* b1 = (const float*)d_in[6];
    const float* W2 = (const float*)d_in[7];
    const float* b2 = (const float*)d_in[8];
    float* out = (float*)d_out;

    const int* row = ei;
    const int* col = ei + NE;

    const size_t HBYTES = (size_t)NN * DH * 4;
    char* p = (char*)d_ws;
    int*   ptr   = (int*)p;  p += (size_t)(NN + 4) * 4;
    int2*  epack = (int2*)p; p += (size_t)NE * 8;
    float* y1    = (float*)p; p += HBYTES;
    float* y2    = (float*)p; p += HBYTES;
    float* hA    = (float*)p; p += HBYTES;
    float* hB    = (float*)p; p += HBYTES;
    unsigned short* Wt0 = (unsigned short*)p; p += (size_t)64 * 192 * 2;
    unsigned short* Wt1 = (unsigned short*)p; p += (size_t)64 * 192 * 2;
    unsigned short* Wt2 = (unsigned short*)p; p += (size_t)64 * 192 * 2;
    // CSR-build transients alias hB (dead before hB first written at layer-1 gemm)
    char* q = (char*)hB;
    unsigned long long* pk = (unsigned long long*)q; q += (size_t)NN * 8;
    float* dinv = (float*)q; q += (size_t)NN * 4;
    int*   cnt  = (int*)q;   q += (size_t)NN * 4;
    int*   excl = (int*)q;   q += (size_t)NN * 4;
    int*   bsum = (int*)q;   q += (size_t)256 * 4;

    // ---- weight prep (tiny) ----
    wprep_kernel<<<48, 256, 0, stream>>>(W0, 64, Wt0);
    wprep_kernel<<<48, 256, 0, stream>>>(W1, 64, Wt1);
    wprep_kernel<<<48, 256, 0, stream>>>(W2, 40, Wt2);

    // ---- CSR build ----
    hipMemsetAsync(pk, 0, (size_t)NN * 8, stream);
    deg_hist_kernel<<<(NE + 255) / 256, 256, 0, stream>>>(row, ea, pk);
    dinv_kernel<<<(NN + 255) / 256, 256, 0, stream>>>(pk, dinv, cnt);
    scan_block_kernel<<<SCAN_NB, SCAN_BS, 0, stream>>>(cnt, excl, bsum);
    scan_bsum_kernel<<<1, 64, 0, stream>>>(bsum);
    ptr_kernel<<<(NN + 255) / 256, 256, 0, stream>>>(excl, bsum, ptr);
    hipMemsetAsync(cnt, 0, (size_t)NN * 4, stream);
    scatter_kernel<<<(NE + 255) / 256, 256, 0, stream>>>(row, col, ea, dinv, ptr, cnt, epack);

    const int SPMV_GRID = (NN * 64 + 255) / 256;
    const int GEMM_GRID = (NN + 63) / 64;

    // ---- layer 0 (h = x) ----
    spmv_csr_kernel<<<SPMV_GRID, 256, 0, stream>>>(ptr, epack, x, y1);
    spmv_csr_kernel<<<SPMV_GRID, 256, 0, stream>>>(ptr, epack, y1, y2);
    gemm3_mfma_kernel<64, 4><<<GEMM_GRID, 256, 0, stream>>>(x, y1, y2, Wt0, b0, hA);

    // ---- layer 1 (h = hA) ----
    spmv_csr_kernel<<<SPMV_GRID, 256, 0, stream>>>(ptr, epack, hA, y1);
    spmv_csr_kernel<<<SPMV_GRID, 256, 0, stream>>>(ptr, epack, y1, y2);
    gemm3_mfma_kernel<64, 4><<<GEMM_GRID, 256, 0, stream>>>(hA, y1, y2, Wt1, b1, hB);

    // ---- layer 2 (h = hB) -> logits into d_out ----
    spmv_csr_kernel<<<SPMV_GRID, 256, 0, stream>>>(ptr, epack, hB, y1);
    spmv_csr_kernel<<<SPMV_GRID, 256, 0, stream>>>(ptr, epack, y1, y2);
    gemm3_mfma_kernel<40, 3><<<GEMM_GRID, 256, 0, stream>>>(hB, y1, y2, Wt2, b2, out);

    // ---- log_softmax in place ----
    lsm_kernel<<<(NN * 64 + 255) / 256, 256, 0, stream>>>(out);
}

// Round 6
// 598.778 us; speedup vs baseline: 4.1187x; 1.2281x over previous
//
#include <hip/hip_runtime.h>
#include <math.h>

#define NN 100000
#define NE 1600000
#define DH 64
#define DO 40
#define SCAN_BS 1024
#define SCAN_NB ((NN + SCAN_BS - 1) / SCAN_BS)   // 98

typedef __attribute__((ext_vector_type(8))) short bf16x8;
typedef __attribute__((ext_vector_type(4))) float f32x4;
typedef __attribute__((ext_vector_type(4))) unsigned short u16x4;

__device__ inline unsigned short f2bf(float f) {   // fp32 -> bf16 RNE
    unsigned u = __float_as_uint(f);
    u = (u + 0x7FFF + ((u >> 16) & 1)) >> 16;
    return (unsigned short)u;
}
__device__ inline float bf2f(unsigned short b) {
    return __uint_as_float((unsigned)b << 16);
}

// ---- packed histogram: pk[row] += (1<<40) | fixpoint24(w) ----
__global__ void deg_hist_kernel(const int* __restrict__ row, const float* __restrict__ w,
                                unsigned long long* __restrict__ pk) {
    int e = blockIdx.x * blockDim.x + threadIdx.x;
    if (e < NE) {
        unsigned long long v = (1ull << 40) |
            (unsigned long long)(unsigned)(w[e] * 16777216.0f + 0.5f);
        atomicAdd(&pk[row[e]], v);
    }
}

// ---- unpack: dinv = deg^-0.5 (0 if deg==0), cnt = edge count ----
__global__ void dinv_kernel(const unsigned long long* __restrict__ pk,
                            float* __restrict__ dinv, int* __restrict__ cnt) {
    int i = blockIdx.x * blockDim.x + threadIdx.x;
    if (i < NN) {
        unsigned long long v = pk[i];
        float d = (float)(v & ((1ull << 40) - 1)) * (1.0f / 16777216.0f);
        dinv[i] = d > 0.f ? 1.0f / sqrtf(d) : 0.f;
        cnt[i] = (int)(v >> 40);
    }
}

// ---- block-level exclusive scan of cnt ----
__global__ __launch_bounds__(SCAN_BS) void scan_block_kernel(const int* __restrict__ cnt,
                                                             int* __restrict__ excl,
                                                             int* __restrict__ bsum) {
    __shared__ int tmp[SCAN_BS];
    int tid = threadIdx.x;
    int i = blockIdx.x * SCAN_BS + tid;
    int v = (i < NN) ? cnt[i] : 0;
    tmp[tid] = v;
    __syncthreads();
    for (int off = 1; off < SCAN_BS; off <<= 1) {
        int t = (tid >= off) ? tmp[tid - off] : 0;
        __syncthreads();
        tmp[tid] += t;
        __syncthreads();
    }
    if (i < NN) excl[i] = tmp[tid] - v;
    if (tid == SCAN_BS - 1) bsum[blockIdx.x] = tmp[tid];
}

__global__ void scan_bsum_kernel(int* __restrict__ bsum) {
    if (threadIdx.x == 0 && blockIdx.x == 0) {
        int run = 0;
        for (int j = 0; j < SCAN_NB; ++j) { int t = bsum[j]; bsum[j] = run; run += t; }
    }
}

__global__ void ptr_kernel(const int* __restrict__ excl, const int* __restrict__ bsum,
                           int* __restrict__ ptr) {
    int i = blockIdx.x * blockDim.x + threadIdx.x;
    if (i < NN) ptr[i] = excl[i] + bsum[i >> 10];
    if (i == 0) ptr[NN] = NE;
}

// ---- scatter edges into CSR order; packed (col, norm) single 8B store ----
__global__ void scatter_kernel(const int* __restrict__ row, const int* __restrict__ col,
                               const float* __restrict__ w, const float* __restrict__ dinv,
                               const int* __restrict__ ptr, int* __restrict__ fill,
                               int2* __restrict__ epack) {
    int e = blockIdx.x * blockDim.x + threadIdx.x;
    if (e < NE) {
        int r = row[e], c = col[e];
        int pos = ptr[r] + atomicAdd(&fill[r], 1);
        float nv = -dinv[r] * w[e] * dinv[c];   // lambda_max = 2
        epack[pos] = make_int2(c, __float_as_int(nv));
    }
}

// ---- x (f32) -> xb (bf16) ----
__global__ void x2bf_kernel(const float* __restrict__ x, unsigned short* __restrict__ xb) {
    int i = blockIdx.x * blockDim.x + threadIdx.x;
    if (i < NN * DH / 4) {
        float4 v = ((const float4*)x)[i];
        u16x4 o = {f2bf(v.x), f2bf(v.y), f2bf(v.z), f2bf(v.w)};
        ((u16x4*)xb)[i] = o;
    }
}

// ---- CSR SpMV: one wave per row, lane = feature, bf16 h rows (128B gather) ----
__global__ __launch_bounds__(256) void spmv_csr_kernel(const int* __restrict__ ptr,
                                                       const int2* __restrict__ epack,
                                                       const unsigned short* __restrict__ h,
                                                       unsigned short* __restrict__ y) {
    int g = blockIdx.x * blockDim.x + threadIdx.x;
    int r = g >> 6, lane = g & 63;
    if (r >= NN) return;
    int s = ptr[r], t = ptr[r + 1];
    float a0 = 0.f, a1 = 0.f, a2 = 0.f, a3 = 0.f;
    float a4 = 0.f, a5 = 0.f, a6 = 0.f, a7 = 0.f;
    for (int base = s; base < t; base += 64) {
        int n = t - base; if (n > 64) n = 64;
        int2 ep = make_int2(0, 0);
        if (lane < n) ep = epack[base + lane];
        int i = 0;
        for (; i + 8 <= n; i += 8) {
            int   c0 = __shfl(ep.x, i);     float w0 = __int_as_float(__shfl(ep.y, i));
            int   c1 = __shfl(ep.x, i + 1); float w1 = __int_as_float(__shfl(ep.y, i + 1));
            int   c2 = __shfl(ep.x, i + 2); float w2 = __int_as_float(__shfl(ep.y, i + 2));
            int   c3 = __shfl(ep.x, i + 3); float w3 = __int_as_float(__shfl(ep.y, i + 3));
            int   c4 = __shfl(ep.x, i + 4); float w4 = __int_as_float(__shfl(ep.y, i + 4));
            int   c5 = __shfl(ep.x, i + 5); float w5 = __int_as_float(__shfl(ep.y, i + 5));
            int   c6 = __shfl(ep.x, i + 6); float w6 = __int_as_float(__shfl(ep.y, i + 6));
            int   c7 = __shfl(ep.x, i + 7); float w7 = __int_as_float(__shfl(ep.y, i + 7));
            unsigned short h0 = h[(size_t)c0 * DH + lane];
            unsigned short h1 = h[(size_t)c1 * DH + lane];
            unsigned short h2 = h[(size_t)c2 * DH + lane];
            unsigned short h3 = h[(size_t)c3 * DH + lane];
            unsigned short h4 = h[(size_t)c4 * DH + lane];
            unsigned short h5 = h[(size_t)c5 * DH + lane];
            unsigned short h6 = h[(size_t)c6 * DH + lane];
            unsigned short h7 = h[(size_t)c7 * DH + lane];
            a0 = fmaf(w0, bf2f(h0), a0); a1 = fmaf(w1, bf2f(h1), a1);
            a2 = fmaf(w2, bf2f(h2), a2); a3 = fmaf(w3, bf2f(h3), a3);
            a4 = fmaf(w4, bf2f(h4), a4); a5 = fmaf(w5, bf2f(h5), a5);
            a6 = fmaf(w6, bf2f(h6), a6); a7 = fmaf(w7, bf2f(h7), a7);
        }
        for (; i < n; ++i) {
            int c = __shfl(ep.x, i); float w = __int_as_float(__shfl(ep.y, i));
            a0 = fmaf(w, bf2f(h[(size_t)c * DH + lane]), a0);
        }
    }
    float res = ((a0 + a1) + (a2 + a3)) + ((a4 + a5) + (a6 + a7));
    y[(size_t)r * DH + lane] = f2bf(res);
}

// ---- weight prep: Wt[n][192] bf16, k = j*64+kin ----
// j=0: W[0]-W[2]; j=1: W[1]; j=2: 2*W[2]   (folds Tx2 = 2*y2 - Tx0 into weights)
__global__ void wprep_kernel(const float* __restrict__ W, int SW,
                             unsigned short* __restrict__ Wt) {
    int idx = blockIdx.x * 256 + threadIdx.x;
    if (idx >= 64 * 192) return;
    int n = idx / 192, k = idx - n * 192;
    int j = k >> 6, kin = k & 63;
    float v = 0.f;
    if (n < SW) {
        if (j == 0)      v = W[kin * SW + n] - W[2 * 64 * SW + kin * SW + n];
        else if (j == 1) v = W[64 * SW + kin * SW + n];
        else             v = 2.f * W[2 * 64 * SW + kin * SW + n];
    }
    Wt[n * 192 + k] = f2bf(v);
}

// ---- MFMA GEMM: out = relu(h@Wt_j0 + y1@Wt_j1 + y2@Wt_j2 + b) ----
// A-operands are bf16 node-feature buffers (direct 16B fragment loads).
// OBF=1 -> bf16 output (hidden layers); OBF=0 -> f32 output (logits).
template<int SW, int NT, int OBF>
__global__ __launch_bounds__(256)
void gemm3_mfma_kernel(const unsigned short* __restrict__ h,
                       const unsigned short* __restrict__ y1,
                       const unsigned short* __restrict__ y2,
                       const unsigned short* __restrict__ Wt,
                       const float* __restrict__ bg, void* __restrict__ outg) {
    int tid = threadIdx.x;
    int w = tid >> 6, l = tid & 63;
    int m = l & 15, kg = l >> 4;
    int node = blockIdx.x * 64 + w * 16 + m;
    int nclamp = node < NN ? node : NN - 1;

    f32x4 acc[NT];
    #pragma unroll
    for (int t = 0; t < NT; ++t) acc[t] = (f32x4){0.f, 0.f, 0.f, 0.f};

    #pragma unroll
    for (int ks = 0; ks < 6; ++ks) {
        const unsigned short* src = (ks < 2) ? h : (ks < 4 ? y1 : y2);
        int kin = (ks & 1) * 32 + kg * 8;
        bf16x8 af = *(const bf16x8*)(src + (size_t)nclamp * DH + kin);
        #pragma unroll
        for (int t = 0; t < NT; ++t) {
            const bf16x8* pb = (const bf16x8*)(Wt + ((size_t)(t * 16 + m) * 192 + ks * 32 + kg * 8));
            acc[t] = __builtin_amdgcn_mfma_f32_16x16x32_bf16(af, *pb, acc[t], 0, 0, 0);
        }
    }

    int orow = blockIdx.x * 64 + w * 16 + kg * 4;   // + r
    #pragma unroll
    for (int t = 0; t < NT; ++t) {
        int oc = t * 16 + m;
        float bias = (oc < SW) ? bg[oc] : 0.f;
        #pragma unroll
        for (int r = 0; r < 4; ++r) {
            int nd = orow + r;
            if (nd < NN && oc < SW) {
                float v = fmaxf(acc[t][r] + bias, 0.f);
                if (OBF) ((unsigned short*)outg)[(size_t)nd * SW + oc] = f2bf(v);
                else     ((float*)outg)[(size_t)nd * SW + oc] = v;
            }
        }
    }
}

// ---- in-place log_softmax over last dim (40) ----
__global__ void lsm_kernel(float* __restrict__ out) {
    int g = blockIdx.x * blockDim.x + threadIdx.x;
    int node = g >> 6, lane = g & 63;
    if (node >= NN) return;
    float v = lane < DO ? out[node * DO + lane] : -INFINITY;
    float m = v;
    #pragma unroll
    for (int off = 32; off > 0; off >>= 1) m = fmaxf(m, __shfl_xor(m, off));
    float ex = lane < DO ? __expf(v - m) : 0.f;
    float s = ex;
    #pragma unroll
    for (int off = 32; off > 0; off >>= 1) s += __shfl_xor(s, off);
    if (lane < DO) out[node * DO + lane] = v - m - __logf(s);
}

extern "C" void kernel_launch(void* const* d_in, const int* in_sizes, int n_in,
                              void* d_out, int out_size, void* d_ws, size_t ws_size,
                              hipStream_t stream) {
    const float* x  = (const float*)d_in[0];
    const int*   ei = (const int*)d_in[1];
    const float* ea = (const float*)d_in[2];
    const float* W0 = (const float*)d_in[3];
    const float* b0 = (const float*)d_in[4];
    const float* W1 = (const float*)d_in[5];
    const float* b1 = (const float*)d_in[6];
    const float* W2 = (const float*)d_in[7];
    const float* b2 = (const float*)d_in[8];
    float* out = (float*)d_out;

    const int* row = ei;
    const int* col = ei + NE;

    const size_t HB2 = (size_t)NN * DH * 2;     // bf16 node-feature buffer
    char* p = (char*)d_ws;
    int*   ptr   = (int*)p;  p += (size_t)(NN + 4) * 4;
    int2*  epack = (int2*)p; p += (size_t)NE * 8;
    unsigned short* xb  = (unsigned short*)p; p += HB2;
    unsigned short* y1b = (unsigned short*)p; p += HB2;
    unsigned short* y2b = (unsigned short*)p; p += HB2;
    unsigned short* hAb = (unsigned short*)p; p += HB2;
    unsigned short* hBb = (unsigned short*)p; p += HB2;
    unsigned short* Wt0 = (unsigned short*)p; p += (size_t)64 * 192 * 2;
    unsigned short* Wt1 = (unsigned short*)p; p += (size_t)64 * 192 * 2;
    unsigned short* Wt2 = (unsigned short*)p; p += (size_t)64 * 192 * 2;
    // CSR-build transients alias hBb (dead before hBb first written at layer-1 gemm)
    char* q = (char*)hBb;
    unsigned long long* pk = (unsigned long long*)q; q += (size_t)NN * 8;
    float* dinv = (float*)q; q += (size_t)NN * 4;
    int*   cnt  = (int*)q;   q += (size_t)NN * 4;
    int*   excl = (int*)q;   q += (size_t)NN * 4;
    int*   bsum = (int*)q;   q += (size_t)256 * 4;

    // ---- weight prep + x conversion (tiny) ----
    wprep_kernel<<<48, 256, 0, stream>>>(W0, 64, Wt0);
    wprep_kernel<<<48, 256, 0, stream>>>(W1, 64, Wt1);
    wprep_kernel<<<48, 256, 0, stream>>>(W2, 40, Wt2);
    x2bf_kernel<<<(NN * DH / 4 + 255) / 256, 256, 0, stream>>>(x, xb);

    // ---- CSR build ----
    hipMemsetAsync(pk, 0, (size_t)NN * 8, stream);
    deg_hist_kernel<<<(NE + 255) / 256, 256, 0, stream>>>(row, ea, pk);
    dinv_kernel<<<(NN + 255) / 256, 256, 0, stream>>>(pk, dinv, cnt);
    scan_block_kernel<<<SCAN_NB, SCAN_BS, 0, stream>>>(cnt, excl, bsum);
    scan_bsum_kernel<<<1, 64, 0, stream>>>(bsum);
    ptr_kernel<<<(NN + 255) / 256, 256, 0, stream>>>(excl, bsum, ptr);
    hipMemsetAsync(cnt, 0, (size_t)NN * 4, stream);
    scatter_kernel<<<(NE + 255) / 256, 256, 0, stream>>>(row, col, ea, dinv, ptr, cnt, epack);

    const int SPMV_GRID = (NN * 64 + 255) / 256;
    const int GEMM_GRID = (NN + 63) / 64;

    // ---- layer 0 (h = xb) ----
    spmv_csr_kernel<<<SPMV_GRID, 256, 0, stream>>>(ptr, epack, xb, y1b);
    spmv_csr_kernel<<<SPMV_GRID, 256, 0, stream>>>(ptr, epack, y1b, y2b);
    gemm3_mfma_kernel<64, 4, 1><<<GEMM_GRID, 256, 0, stream>>>(xb, y1b, y2b, Wt0, b0, hAb);

    // ---- layer 1 (h = hAb) ----
    spmv_csr_kernel<<<SPMV_GRID, 256, 0, stream>>>(ptr, epack, hAb, y1b);
    spmv_csr_kernel<<<SPMV_GRID, 256, 0, stream>>>(ptr, epack, y1b, y2b);
    gemm3_mfma_kernel<64, 4, 1><<<GEMM_GRID, 256, 0, stream>>>(hAb, y1b, y2b, Wt1, b1, hBb);

    // ---- layer 2 (h = hBb) -> f32 logits into d_out ----
    spmv_csr_kernel<<<SPMV_GRID, 256, 0, stream>>>(ptr, epack, hBb, y1b);
    spmv_csr_kernel<<<SPMV_GRID, 256, 0, stream>>>(ptr, epack, y1b, y2b);
    gemm3_mfma_kernel<40, 3, 0><<<GEMM_GRID, 256, 0, stream>>>(hBb, y1b, y2b, Wt2, b2, out);

    // ---- log_softmax in place ----
    lsm_kernel<<<(NN * 64 + 255) / 256, 256, 0, stream>>>(out);
}

// Round 7
// 580.949 us; speedup vs baseline: 4.2451x; 1.0307x over previous
//
#include <hip/hip_runtime.h>
#include <math.h>

#define NN 100000
#define NE 1600000
#define DH 64
#define DO 40
#define SCAN_BS 1024
#define SCAN_NB ((NN + SCAN_BS - 1) / SCAN_BS)   // 98

typedef __attribute__((ext_vector_type(8))) short bf16x8;
typedef __attribute__((ext_vector_type(4))) float f32x4;
typedef __attribute__((ext_vector_type(4))) unsigned short u16x4;

__device__ inline unsigned short f2bf(float f) {   // fp32 -> bf16 RNE
    unsigned u = __float_as_uint(f);
    u = (u + 0x7FFF + ((u >> 16) & 1)) >> 16;
    return (unsigned short)u;
}
__device__ inline float bf2f(unsigned short b) {
    return __uint_as_float((unsigned)b << 16);
}

// ---- packed histogram: pk[row] += (1<<40)|fix24(w); returned old count = rank ----
__global__ void deg_hist_kernel(const int* __restrict__ row, const float* __restrict__ w,
                                unsigned long long* __restrict__ pk, int* __restrict__ rank) {
    int e = blockIdx.x * blockDim.x + threadIdx.x;
    if (e < NE) {
        unsigned long long v = (1ull << 40) |
            (unsigned long long)(unsigned)(w[e] * 16777216.0f + 0.5f);
        unsigned long long old = atomicAdd(&pk[row[e]], v);
        rank[e] = (int)(old >> 40);
    }
}

// ---- unpack: dinv = deg^-0.5 (0 if deg==0), cnt = edge count ----
__global__ void dinv_kernel(const unsigned long long* __restrict__ pk,
                            float* __restrict__ dinv, int* __restrict__ cnt) {
    int i = blockIdx.x * blockDim.x + threadIdx.x;
    if (i < NN) {
        unsigned long long v = pk[i];
        float d = (float)(v & ((1ull << 40) - 1)) * (1.0f / 16777216.0f);
        dinv[i] = d > 0.f ? 1.0f / sqrtf(d) : 0.f;
        cnt[i] = (int)(v >> 40);
    }
}

// ---- block-level exclusive scan of cnt ----
__global__ __launch_bounds__(SCAN_BS) void scan_block_kernel(const int* __restrict__ cnt,
                                                             int* __restrict__ excl,
                                                             int* __restrict__ bsum) {
    __shared__ int tmp[SCAN_BS];
    int tid = threadIdx.x;
    int i = blockIdx.x * SCAN_BS + tid;
    int v = (i < NN) ? cnt[i] : 0;
    tmp[tid] = v;
    __syncthreads();
    for (int off = 1; off < SCAN_BS; off <<= 1) {
        int t = (tid >= off) ? tmp[tid - off] : 0;
        __syncthreads();
        tmp[tid] += t;
        __syncthreads();
    }
    if (i < NN) excl[i] = tmp[tid] - v;
    if (tid == SCAN_BS - 1) bsum[blockIdx.x] = tmp[tid];
}

__global__ void scan_bsum_kernel(int* __restrict__ bsum) {
    if (threadIdx.x == 0 && blockIdx.x == 0) {
        int run = 0;
        for (int j = 0; j < SCAN_NB; ++j) { int t = bsum[j]; bsum[j] = run; run += t; }
    }
}

__global__ void ptr_kernel(const int* __restrict__ excl, const int* __restrict__ bsum,
                           int* __restrict__ ptr) {
    int i = blockIdx.x * blockDim.x + threadIdx.x;
    if (i < NN) ptr[i] = excl[i] + bsum[i >> 10];
    if (i == 0) ptr[NN] = NE;
}

// ---- scatter edges into CSR order (atomic-free: pos = ptr[row] + rank) ----
__global__ void scatter_kernel(const int* __restrict__ row, const int* __restrict__ col,
                               const float* __restrict__ w, const float* __restrict__ dinv,
                               const int* __restrict__ ptr, const int* __restrict__ rank,
                               int2* __restrict__ epack) {
    int e = blockIdx.x * blockDim.x + threadIdx.x;
    if (e < NE) {
        int r = row[e], c = col[e];
        int pos = ptr[r] + rank[e];
        float nv = -dinv[r] * w[e] * dinv[c];   // lambda_max = 2
        epack[pos] = make_int2(c, __float_as_int(nv));
    }
}

// ---- x (f32) -> xb (bf16) ----
__global__ void x2bf_kernel(const float* __restrict__ x, unsigned short* __restrict__ xb) {
    int i = blockIdx.x * blockDim.x + threadIdx.x;
    if (i < NN * DH / 4) {
        float4 v = ((const float4*)x)[i];
        u16x4 o = {f2bf(v.x), f2bf(v.y), f2bf(v.z), f2bf(v.w)};
        ((u16x4*)xb)[i] = o;
    }
}

// ---- CSR SpMV: one wave per row, lane = feature, bf16 rows, 16-deep gather ILP ----
__global__ __launch_bounds__(256) void spmv_csr_kernel(const int* __restrict__ ptr,
                                                       const int2* __restrict__ epack,
                                                       const unsigned short* __restrict__ h,
                                                       unsigned short* __restrict__ y) {
    int g = blockIdx.x * blockDim.x + threadIdx.x;
    int r = g >> 6, lane = g & 63;
    if (r >= NN) return;
    int s = ptr[r], t = ptr[r + 1];
    float a0 = 0.f, a1 = 0.f, a2 = 0.f, a3 = 0.f;
    float a4 = 0.f, a5 = 0.f, a6 = 0.f, a7 = 0.f;
    for (int base = s; base < t; base += 64) {
        int n = t - base; if (n > 64) n = 64;
        int2 ep = make_int2(0, 0);
        if (lane < n) ep = epack[base + lane];
        int i = 0;
        for (; i + 16 <= n; i += 16) {
            int   c0 = __shfl(ep.x, i);      float w0 = __int_as_float(__shfl(ep.y, i));
            int   c1 = __shfl(ep.x, i + 1);  float w1 = __int_as_float(__shfl(ep.y, i + 1));
            int   c2 = __shfl(ep.x, i + 2);  float w2 = __int_as_float(__shfl(ep.y, i + 2));
            int   c3 = __shfl(ep.x, i + 3);  float w3 = __int_as_float(__shfl(ep.y, i + 3));
            int   c4 = __shfl(ep.x, i + 4);  float w4 = __int_as_float(__shfl(ep.y, i + 4));
            int   c5 = __shfl(ep.x, i + 5);  float w5 = __int_as_float(__shfl(ep.y, i + 5));
            int   c6 = __shfl(ep.x, i + 6);  float w6 = __int_as_float(__shfl(ep.y, i + 6));
            int   c7 = __shfl(ep.x, i + 7);  float w7 = __int_as_float(__shfl(ep.y, i + 7));
            int   c8 = __shfl(ep.x, i + 8);  float w8 = __int_as_float(__shfl(ep.y, i + 8));
            int   c9 = __shfl(ep.x, i + 9);  float w9 = __int_as_float(__shfl(ep.y, i + 9));
            int   cA = __shfl(ep.x, i + 10); float wA = __int_as_float(__shfl(ep.y, i + 10));
            int   cB = __shfl(ep.x, i + 11); float wB = __int_as_float(__shfl(ep.y, i + 11));
            int   cC = __shfl(ep.x, i + 12); float wC = __int_as_float(__shfl(ep.y, i + 12));
            int   cD = __shfl(ep.x, i + 13); float wD = __int_as_float(__shfl(ep.y, i + 13));
            int   cE = __shfl(ep.x, i + 14); float wE = __int_as_float(__shfl(ep.y, i + 14));
            int   cF = __shfl(ep.x, i + 15); float wF = __int_as_float(__shfl(ep.y, i + 15));
            unsigned short h0 = h[(size_t)c0 * DH + lane];
            unsigned short h1 = h[(size_t)c1 * DH + lane];
            unsigned short h2 = h[(size_t)c2 * DH + lane];
            unsigned short h3 = h[(size_t)c3 * DH + lane];
            unsigned short h4 = h[(size_t)c4 * DH + lane];
            unsigned short h5 = h[(size_t)c5 * DH + lane];
            unsigned short h6 = h[(size_t)c6 * DH + lane];
            unsigned short h7 = h[(size_t)c7 * DH + lane];
            unsigned short h8 = h[(size_t)c8 * DH + lane];
            unsigned short h9 = h[(size_t)c9 * DH + lane];
            unsigned short hA = h[(size_t)cA * DH + lane];
            unsigned short hB = h[(size_t)cB * DH + lane];
            unsigned short hC = h[(size_t)cC * DH + lane];
            unsigned short hD = h[(size_t)cD * DH + lane];
            unsigned short hE = h[(size_t)cE * DH + lane];
            unsigned short hF = h[(size_t)cF * DH + lane];
            a0 = fmaf(w0, bf2f(h0), a0); a1 = fmaf(w1, bf2f(h1), a1);
            a2 = fmaf(w2, bf2f(h2), a2); a3 = fmaf(w3, bf2f(h3), a3);
            a4 = fmaf(w4, bf2f(h4), a4); a5 = fmaf(w5, bf2f(h5), a5);
            a6 = fmaf(w6, bf2f(h6), a6); a7 = fmaf(w7, bf2f(h7), a7);
            a0 = fmaf(w8, bf2f(h8), a0); a1 = fmaf(w9, bf2f(h9), a1);
            a2 = fmaf(wA, bf2f(hA), a2); a3 = fmaf(wB, bf2f(hB), a3);
            a4 = fmaf(wC, bf2f(hC), a4); a5 = fmaf(wD, bf2f(hD), a5);
            a6 = fmaf(wE, bf2f(hE), a6); a7 = fmaf(wF, bf2f(hF), a7);
        }
        for (; i + 8 <= n; i += 8) {
            int   c0 = __shfl(ep.x, i);     float w0 = __int_as_float(__shfl(ep.y, i));
            int   c1 = __shfl(ep.x, i + 1); float w1 = __int_as_float(__shfl(ep.y, i + 1));
            int   c2 = __shfl(ep.x, i + 2); float w2 = __int_as_float(__shfl(ep.y, i + 2));
            int   c3 = __shfl(ep.x, i + 3); float w3 = __int_as_float(__shfl(ep.y, i + 3));
            int   c4 = __shfl(ep.x, i + 4); float w4 = __int_as_float(__shfl(ep.y, i + 4));
            int   c5 = __shfl(ep.x, i + 5); float w5 = __int_as_float(__shfl(ep.y, i + 5));
            int   c6 = __shfl(ep.x, i + 6); float w6 = __int_as_float(__shfl(ep.y, i + 6));
            int   c7 = __shfl(ep.x, i + 7); float w7 = __int_as_float(__shfl(ep.y, i + 7));
            unsigned short h0 = h[(size_t)c0 * DH + lane];
            unsigned short h1 = h[(size_t)c1 * DH + lane];
            unsigned short h2 = h[(size_t)c2 * DH + lane];
            unsigned short h3 = h[(size_t)c3 * DH + lane];
            unsigned short h4 = h[(size_t)c4 * DH + lane];
            unsigned short h5 = h[(size_t)c5 * DH + lane];
            unsigned short h6 = h[(size_t)c6 * DH + lane];
            unsigned short h7 = h[(size_t)c7 * DH + lane];
            a0 = fmaf(w0, bf2f(h0), a0); a1 = fmaf(w1, bf2f(h1), a1);
            a2 = fmaf(w2, bf2f(h2), a2); a3 = fmaf(w3, bf2f(h3), a3);
            a4 = fmaf(w4, bf2f(h4), a4); a5 = fmaf(w5, bf2f(h5), a5);
            a6 = fmaf(w6, bf2f(h6), a6); a7 = fmaf(w7, bf2f(h7), a7);
        }
        for (; i < n; ++i) {
            int c = __shfl(ep.x, i); float w = __int_as_float(__shfl(ep.y, i));
            a0 = fmaf(w, bf2f(h[(size_t)c * DH + lane]), a0);
        }
    }
    float res = ((a0 + a1) + (a2 + a3)) + ((a4 + a5) + (a6 + a7));
    y[(size_t)r * DH + lane] = f2bf(res);
}

// ---- weight prep: Wt[n][192] bf16, k = j*64+kin ----
// j=0: W[0]-W[2]; j=1: W[1]; j=2: 2*W[2]   (folds Tx2 = 2*y2 - Tx0 into weights)
__global__ void wprep_kernel(const float* __restrict__ W, int SW,
                             unsigned short* __restrict__ Wt) {
    int idx = blockIdx.x * 256 + threadIdx.x;
    if (idx >= 64 * 192) return;
    int n = idx / 192, k = idx - n * 192;
    int j = k >> 6, kin = k & 63;
    float v = 0.f;
    if (n < SW) {
        if (j == 0)      v = W[kin * SW + n] - W[2 * 64 * SW + kin * SW + n];
        else if (j == 1) v = W[64 * SW + kin * SW + n];
        else             v = 2.f * W[2 * 64 * SW + kin * SW + n];
    }
    Wt[n * 192 + k] = f2bf(v);
}

// ---- MFMA GEMM: out = relu(h@Wt_j0 + y1@Wt_j1 + y2@Wt_j2 + b) ----
template<int SW, int NT, int OBF>
__global__ __launch_bounds__(256)
void gemm3_mfma_kernel(const unsigned short* __restrict__ h,
                       const unsigned short* __restrict__ y1,
                       const unsigned short* __restrict__ y2,
                       const unsigned short* __restrict__ Wt,
                       const float* __restrict__ bg, void* __restrict__ outg) {
    int tid = threadIdx.x;
    int w = tid >> 6, l = tid & 63;
    int m = l & 15, kg = l >> 4;
    int node = blockIdx.x * 64 + w * 16 + m;
    int nclamp = node < NN ? node : NN - 1;

    f32x4 acc[NT];
    #pragma unroll
    for (int t = 0; t < NT; ++t) acc[t] = (f32x4){0.f, 0.f, 0.f, 0.f};

    #pragma unroll
    for (int ks = 0; ks < 6; ++ks) {
        const unsigned short* src = (ks < 2) ? h : (ks < 4 ? y1 : y2);
        int kin = (ks & 1) * 32 + kg * 8;
        bf16x8 af = *(const bf16x8*)(src + (size_t)nclamp * DH + kin);
        #pragma unroll
        for (int t = 0; t < NT; ++t) {
            const bf16x8* pb = (const bf16x8*)(Wt + ((size_t)(t * 16 + m) * 192 + ks * 32 + kg * 8));
            acc[t] = __builtin_amdgcn_mfma_f32_16x16x32_bf16(af, *pb, acc[t], 0, 0, 0);
        }
    }

    int orow = blockIdx.x * 64 + w * 16 + kg * 4;   // + r
    #pragma unroll
    for (int t = 0; t < NT; ++t) {
        int oc = t * 16 + m;
        float bias = (oc < SW) ? bg[oc] : 0.f;
        #pragma unroll
        for (int r = 0; r < 4; ++r) {
            int nd = orow + r;
            if (nd < NN && oc < SW) {
                float v = fmaxf(acc[t][r] + bias, 0.f);
                if (OBF) ((unsigned short*)outg)[(size_t)nd * SW + oc] = f2bf(v);
                else     ((float*)outg)[(size_t)nd * SW + oc] = v;
            }
        }
    }
}

// ---- in-place log_softmax over last dim (40) ----
__global__ void lsm_kernel(float* __restrict__ out) {
    int g = blockIdx.x * blockDim.x + threadIdx.x;
    int node = g >> 6, lane = g & 63;
    if (node >= NN) return;
    float v = lane < DO ? out[node * DO + lane] : -INFINITY;
    float m = v;
    #pragma unroll
    for (int off = 32; off > 0; off >>= 1) m = fmaxf(m, __shfl_xor(m, off));
    float ex = lane < DO ? __expf(v - m) : 0.f;
    float s = ex;
    #pragma unroll
    for (int off = 32; off > 0; off >>= 1) s += __shfl_xor(s, off);
    if (lane < DO) out[node * DO + lane] = v - m - __logf(s);
}

extern "C" void kernel_launch(void* const* d_in, const int* in_sizes, int n_in,
                              void* d_out, int out_size, void* d_ws, size_t ws_size,
                              hipStream_t stream) {
    const float* x  = (const float*)d_in[0];
    const int*   ei = (const int*)d_in[1];
    const float* ea = (const float*)d_in[2];
    const float* W0 = (const float*)d_in[3];
    const float* b0 = (const float*)d_in[4];
    const float* W1 = (const float*)d_in[5];
    const float* b1 = (const float*)d_in[6];
    const float* W2 = (const float*)d_in[7];
    const float* b2 = (const float*)d_in[8];
    float* out = (float*)d_out;

    const int* row = ei;
    const int* col = ei + NE;

    const size_t HB2 = (size_t)NN * DH * 2;     // bf16 node-feature buffer
    char* p = (char*)d_ws;
    int*   ptr   = (int*)p;  p += (size_t)(NN + 4) * 4;
    int2*  epack = (int2*)p; p += (size_t)NE * 8;
    int*   rank  = (int*)p;  p += (size_t)NE * 4;
    unsigned short* xb  = (unsigned short*)p; p += HB2;
    unsigned short* y1b = (unsigned short*)p; p += HB2;
    unsigned short* y2b = (unsigned short*)p; p += HB2;
    unsigned short* hAb = (unsigned short*)p; p += HB2;
    unsigned short* hBb = (unsigned short*)p; p += HB2;
    unsigned short* Wt0 = (unsigned short*)p; p += (size_t)64 * 192 * 2;
    unsigned short* Wt1 = (unsigned short*)p; p += (size_t)64 * 192 * 2;
    unsigned short* Wt2 = (unsigned short*)p; p += (size_t)64 * 192 * 2;
    // CSR-build transients alias hBb (dead before hBb first written at layer-1 gemm)
    char* q = (char*)hBb;
    unsigned long long* pk = (unsigned long long*)q; q += (size_t)NN * 8;
    float* dinv = (float*)q; q += (size_t)NN * 4;
    int*   cnt  = (int*)q;   q += (size_t)NN * 4;
    int*   excl = (int*)q;   q += (size_t)NN * 4;
    int*   bsum = (int*)q;   q += (size_t)256 * 4;

    // ---- weight prep + x conversion (tiny) ----
    wprep_kernel<<<48, 256, 0, stream>>>(W0, 64, Wt0);
    wprep_kernel<<<48, 256, 0, stream>>>(W1, 64, Wt1);
    wprep_kernel<<<48, 256, 0, stream>>>(W2, 40, Wt2);
    x2bf_kernel<<<(NN * DH / 4 + 255) / 256, 256, 0, stream>>>(x, xb);

    // ---- CSR build (atomic-free scatter via rank from deg_hist) ----
    hipMemsetAsync(pk, 0, (size_t)NN * 8, stream);
    deg_hist_kernel<<<(NE + 255) / 256, 256, 0, stream>>>(row, ea, pk, rank);
    dinv_kernel<<<(NN + 255) / 256, 256, 0, stream>>>(pk, dinv, cnt);
    scan_block_kernel<<<SCAN_NB, SCAN_BS, 0, stream>>>(cnt, excl, bsum);
    scan_bsum_kernel<<<1, 64, 0, stream>>>(bsum);
    ptr_kernel<<<(NN + 255) / 256, 256, 0, stream>>>(excl, bsum, ptr);
    scatter_kernel<<<(NE + 255) / 256, 256, 0, stream>>>(row, col, ea, dinv, ptr, rank, epack);

    const int SPMV_GRID = (NN * 64 + 255) / 256;
    const int GEMM_GRID = (NN + 63) / 64;

    // ---- layer 0 (h = xb) ----
    spmv_csr_kernel<<<SPMV_GRID, 256, 0, stream>>>(ptr, epack, xb, y1b);
    spmv_csr_kernel<<<SPMV_GRID, 256, 0, stream>>>(ptr, epack, y1b, y2b);
    gemm3_mfma_kernel<64, 4, 1><<<GEMM_GRID, 256, 0, stream>>>(xb, y1b, y2b, Wt0, b0, hAb);

    // ---- layer 1 (h = hAb) ----
    spmv_csr_kernel<<<SPMV_GRID, 256, 0, stream>>>(ptr, epack, hAb, y1b);
    spmv_csr_kernel<<<SPMV_GRID, 256, 0, stream>>>(ptr, epack, y1b, y2b);
    gemm3_mfma_kernel<64, 4, 1><<<GEMM_GRID, 256, 0, stream>>>(hAb, y1b, y2b, Wt1, b1, hBb);

    // ---- layer 2 (h = hBb) -> f32 logits into d_out ----
    spmv_csr_kernel<<<SPMV_GRID, 256, 0, stream>>>(ptr, epack, hBb, y1b);
    spmv_csr_kernel<<<SPMV_GRID, 256, 0, stream>>>(ptr, epack, y1b, y2b);
    gemm3_mfma_kernel<40, 3, 0><<<GEMM_GRID, 256, 0, stream>>>(hBb, y1b, y2b, Wt2, b2, out);

    // ---- log_softmax in place ----
    lsm_kernel<<<(NN * 64 + 255) / 256, 256, 0, stream>>>(out);
}

// Round 8
// 531.805 us; speedup vs baseline: 4.6374x; 1.0924x over previous
//
#include <hip/hip_runtime.h>
#include <math.h>

#define NN 100000
#define NE 1600000
#define DH 64
#define DO 40
#define NBKT ((NN + 255) >> 8)                 // 391 buckets of 256 rows
#define P3B 256                                 // blocks in binning passes
#define EPB ((NE + P3B - 1) / P3B)              // 6250 edges per block (exact)

typedef __attribute__((ext_vector_type(8))) short bf16x8;
typedef __attribute__((ext_vector_type(4))) float f32x4;
typedef __attribute__((ext_vector_type(4))) unsigned short u16x4;

__device__ inline unsigned short f2bf(float f) {   // fp32 -> bf16 RNE
    unsigned u = __float_as_uint(f);
    u = (u + 0x7FFF + ((u >> 16) & 1)) >> 16;
    return (unsigned short)u;
}
__device__ inline float bf2f(unsigned short b) {
    return __uint_as_float((unsigned)b << 16);
}

// ---- pass 1: bucket histogram (LDS-aggregated; ~100K global atomics) ----
__global__ __launch_bounds__(1024) void bin_count_kernel(const int* __restrict__ row,
                                                         int* __restrict__ bcnt) {
    __shared__ int h[NBKT];
    for (int i = threadIdx.x; i < NBKT; i += 1024) h[i] = 0;
    __syncthreads();
    int base = blockIdx.x * EPB;
    int end = base + EPB; if (end > NE) end = NE;
    for (int e = base + threadIdx.x; e < end; e += 1024)
        atomicAdd(&h[row[e] >> 8], 1);
    __syncthreads();
    for (int i = threadIdx.x; i < NBKT; i += 1024)
        if (h[i]) atomicAdd(&bcnt[i], h[i]);
}

// ---- pass 2: scan bucket counts -> bbase, gcur; set ptr[NN] ----
__global__ __launch_bounds__(512) void bscan_kernel(const int* __restrict__ bcnt,
                                                    int* __restrict__ bbase,
                                                    int* __restrict__ gcur,
                                                    int* __restrict__ ptr) {
    __shared__ int tmp[512];
    int tid = threadIdx.x;
    int v = (tid < NBKT) ? bcnt[tid] : 0;
    tmp[tid] = v;
    __syncthreads();
    for (int off = 1; off < 512; off <<= 1) {
        int t = (tid >= off) ? tmp[tid - off] : 0;
        __syncthreads();
        tmp[tid] += t;
        __syncthreads();
    }
    if (tid < NBKT) { int excl = tmp[tid] - v; bbase[tid] = excl; gcur[tid] = excl; }
    if (tid == 0) { bbase[NBKT] = NE; ptr[NN] = NE; }
}

// ---- pass 3: scatter edges to bucket-contiguous order (LDS cursors) ----
// binned[pos] = ( (row_local<<17) | col , w )
__global__ __launch_bounds__(1024) void bin_scatter_kernel(const int* __restrict__ row,
                                                           const int* __restrict__ col,
                                                           const float* __restrict__ w,
                                                           int* __restrict__ gcur,
                                                           int2* __restrict__ binned) {
    __shared__ int h[NBKT];
    __shared__ int cur[NBKT];
    for (int i = threadIdx.x; i < NBKT; i += 1024) h[i] = 0;
    __syncthreads();
    int base = blockIdx.x * EPB;
    int end = base + EPB; if (end > NE) end = NE;
    for (int e = base + threadIdx.x; e < end; e += 1024)
        atomicAdd(&h[row[e] >> 8], 1);
    __syncthreads();
    for (int i = threadIdx.x; i < NBKT; i += 1024)
        cur[i] = h[i] ? atomicAdd(&gcur[i], h[i]) : 0;
    __syncthreads();
    for (int e = base + threadIdx.x; e < end; e += 1024) {
        int r = row[e];
        int b = r >> 8;
        int pos = atomicAdd(&cur[b], 1);
        binned[pos] = make_int2(((r & 255) << 17) | col[e], __float_as_int(w[e]));
    }
}

// ---- pass 4: per-bucket CSR finalize: cnt/deg in LDS, scan, ptr, dinv,
//      place edges with partial weight t = -w * dinv[row] ----
__global__ __launch_bounds__(1024) void bfin_kernel(const int* __restrict__ bbase,
                                                    const int2* __restrict__ binned,
                                                    int* __restrict__ ptr,
                                                    float* __restrict__ dinv,
                                                    int2* __restrict__ epack) {
    __shared__ int cnt[256];
    __shared__ float deg[256];
    __shared__ int tmp[256];
    __shared__ int cur[256];
    __shared__ float sdv[256];
    int b = blockIdx.x;
    int s = bbase[b], t = bbase[b + 1];
    int tid = threadIdx.x;
    if (tid < 256) { cnt[tid] = 0; deg[tid] = 0.f; }
    __syncthreads();
    for (int i = s + tid; i < t; i += 1024) {
        int2 ep = binned[i];
        int rl = ((unsigned)ep.x) >> 17;
        atomicAdd(&cnt[rl], 1);
        atomicAdd(&deg[rl], __int_as_float(ep.y));
    }
    __syncthreads();
    if (tid < 256) tmp[tid] = cnt[tid];
    __syncthreads();
    for (int off = 1; off < 256; off <<= 1) {
        int tv = 0;
        if (tid < 256 && tid >= off) tv = tmp[tid - off];
        __syncthreads();
        if (tid < 256) tmp[tid] += tv;
        __syncthreads();
    }
    if (tid < 256) {
        int excl = tmp[tid] - cnt[tid];
        cur[tid] = excl;
        float d = deg[tid];
        float dv = d > 0.f ? 1.0f / sqrtf(d) : 0.f;
        sdv[tid] = dv;
        int r = (b << 8) + tid;
        if (r < NN) { ptr[r] = s + excl; dinv[r] = dv; }
    }
    __syncthreads();
    for (int i = s + tid; i < t; i += 1024) {
        int2 ep = binned[i];
        int rl = ((unsigned)ep.x) >> 17;
        int c = ep.x & 0x1FFFF;
        int lr = atomicAdd(&cur[rl], 1);
        float tp = -__int_as_float(ep.y) * sdv[rl];
        epack[s + lr] = make_int2(c, __float_as_int(tp));
    }
}

// ---- pass 5: env finalize: nv = t * dinv[col] ----
__global__ void env_kernel(const float* __restrict__ dinv, int2* __restrict__ epack) {
    int e = blockIdx.x * blockDim.x + threadIdx.x;
    if (e < NE) {
        int2 ep = epack[e];
        ep.y = __float_as_int(__int_as_float(ep.y) * dinv[ep.x]);
        epack[e] = ep;
    }
}

// ---- x (f32) -> xb (bf16) ----
__global__ void x2bf_kernel(const float* __restrict__ x, unsigned short* __restrict__ xb) {
    int i = blockIdx.x * blockDim.x + threadIdx.x;
    if (i < NN * DH / 4) {
        float4 v = ((const float4*)x)[i];
        u16x4 o = {f2bf(v.x), f2bf(v.y), f2bf(v.z), f2bf(v.w)};
        ((u16x4*)xb)[i] = o;
    }
}

// ---- CSR SpMV: one wave per row, lane = feature, bf16 rows, 16-deep gather ILP ----
__global__ __launch_bounds__(256) void spmv_csr_kernel(const int* __restrict__ ptr,
                                                       const int2* __restrict__ epack,
                                                       const unsigned short* __restrict__ h,
                                                       unsigned short* __restrict__ y) {
    int g = blockIdx.x * blockDim.x + threadIdx.x;
    int r = g >> 6, lane = g & 63;
    if (r >= NN) return;
    int s = ptr[r], t = ptr[r + 1];
    float a0 = 0.f, a1 = 0.f, a2 = 0.f, a3 = 0.f;
    float a4 = 0.f, a5 = 0.f, a6 = 0.f, a7 = 0.f;
    for (int base = s; base < t; base += 64) {
        int n = t - base; if (n > 64) n = 64;
        int2 ep = make_int2(0, 0);
        if (lane < n) ep = epack[base + lane];
        int i = 0;
        for (; i + 16 <= n; i += 16) {
            int   c0 = __shfl(ep.x, i);      float w0 = __int_as_float(__shfl(ep.y, i));
            int   c1 = __shfl(ep.x, i + 1);  float w1 = __int_as_float(__shfl(ep.y, i + 1));
            int   c2 = __shfl(ep.x, i + 2);  float w2 = __int_as_float(__shfl(ep.y, i + 2));
            int   c3 = __shfl(ep.x, i + 3);  float w3 = __int_as_float(__shfl(ep.y, i + 3));
            int   c4 = __shfl(ep.x, i + 4);  float w4 = __int_as_float(__shfl(ep.y, i + 4));
            int   c5 = __shfl(ep.x, i + 5);  float w5 = __int_as_float(__shfl(ep.y, i + 5));
            int   c6 = __shfl(ep.x, i + 6);  float w6 = __int_as_float(__shfl(ep.y, i + 6));
            int   c7 = __shfl(ep.x, i + 7);  float w7 = __int_as_float(__shfl(ep.y, i + 7));
            int   c8 = __shfl(ep.x, i + 8);  float w8 = __int_as_float(__shfl(ep.y, i + 8));
            int   c9 = __shfl(ep.x, i + 9);  float w9 = __int_as_float(__shfl(ep.y, i + 9));
            int   cA = __shfl(ep.x, i + 10); float wA = __int_as_float(__shfl(ep.y, i + 10));
            int   cB = __shfl(ep.x, i + 11); float wB = __int_as_float(__shfl(ep.y, i + 11));
            int   cC = __shfl(ep.x, i + 12); float wC = __int_as_float(__shfl(ep.y, i + 12));
            int   cD = __shfl(ep.x, i + 13); float wD = __int_as_float(__shfl(ep.y, i + 13));
            int   cE = __shfl(ep.x, i + 14); float wE = __int_as_float(__shfl(ep.y, i + 14));
            int   cF = __shfl(ep.x, i + 15); float wF = __int_as_float(__shfl(ep.y, i + 15));
            unsigned short h0 = h[(size_t)c0 * DH + lane];
            unsigned short h1 = h[(size_t)c1 * DH + lane];
            unsigned short h2 = h[(size_t)c2 * DH + lane];
            unsigned short h3 = h[(size_t)c3 * DH + lane];
            unsigned short h4 = h[(size_t)c4 * DH + lane];
            unsigned short h5 = h[(size_t)c5 * DH + lane];
            unsigned short h6 = h[(size_t)c6 * DH + lane];
            unsigned short h7 = h[(size_t)c7 * DH + lane];
            unsigned short h8 = h[(size_t)c8 * DH + lane];
            unsigned short h9 = h[(size_t)c9 * DH + lane];
            unsigned short hA = h[(size_t)cA * DH + lane];
            unsigned short hB = h[(size_t)cB * DH + lane];
            unsigned short hC = h[(size_t)cC * DH + lane];
            unsigned short hD = h[(size_t)cD * DH + lane];
            unsigned short hE = h[(size_t)cE * DH + lane];
            unsigned short hF = h[(size_t)cF * DH + lane];
            a0 = fmaf(w0, bf2f(h0), a0); a1 = fmaf(w1, bf2f(h1), a1);
            a2 = fmaf(w2, bf2f(h2), a2); a3 = fmaf(w3, bf2f(h3), a3);
            a4 = fmaf(w4, bf2f(h4), a4); a5 = fmaf(w5, bf2f(h5), a5);
            a6 = fmaf(w6, bf2f(h6), a6); a7 = fmaf(w7, bf2f(h7), a7);
            a0 = fmaf(w8, bf2f(h8), a0); a1 = fmaf(w9, bf2f(h9), a1);
            a2 = fmaf(wA, bf2f(hA), a2); a3 = fmaf(wB, bf2f(hB), a3);
            a4 = fmaf(wC, bf2f(hC), a4); a5 = fmaf(wD, bf2f(hD), a5);
            a6 = fmaf(wE, bf2f(hE), a6); a7 = fmaf(wF, bf2f(hF), a7);
        }
        for (; i + 8 <= n; i += 8) {
            int   c0 = __shfl(ep.x, i);     float w0 = __int_as_float(__shfl(ep.y, i));
            int   c1 = __shfl(ep.x, i + 1); float w1 = __int_as_float(__shfl(ep.y, i + 1));
            int   c2 = __shfl(ep.x, i + 2); float w2 = __int_as_float(__shfl(ep.y, i + 2));
            int   c3 = __shfl(ep.x, i + 3); float w3 = __int_as_float(__shfl(ep.y, i + 3));
            int   c4 = __shfl(ep.x, i + 4); float w4 = __int_as_float(__shfl(ep.y, i + 4));
            int   c5 = __shfl(ep.x, i + 5); float w5 = __int_as_float(__shfl(ep.y, i + 5));
            int   c6 = __shfl(ep.x, i + 6); float w6 = __int_as_float(__shfl(ep.y, i + 6));
            int   c7 = __shfl(ep.x, i + 7); float w7 = __int_as_float(__shfl(ep.y, i + 7));
            unsigned short h0 = h[(size_t)c0 * DH + lane];
            unsigned short h1 = h[(size_t)c1 * DH + lane];
            unsigned short h2 = h[(size_t)c2 * DH + lane];
            unsigned short h3 = h[(size_t)c3 * DH + lane];
            unsigned short h4 = h[(size_t)c4 * DH + lane];
            unsigned short h5 = h[(size_t)c5 * DH + lane];
            unsigned short h6 = h[(size_t)c6 * DH + lane];
            unsigned short h7 = h[(size_t)c7 * DH + lane];
            a0 = fmaf(w0, bf2f(h0), a0); a1 = fmaf(w1, bf2f(h1), a1);
            a2 = fmaf(w2, bf2f(h2), a2); a3 = fmaf(w3, bf2f(h3), a3);
            a4 = fmaf(w4, bf2f(h4), a4); a5 = fmaf(w5, bf2f(h5), a5);
            a6 = fmaf(w6, bf2f(h6), a6); a7 = fmaf(w7, bf2f(h7), a7);
        }
        for (; i < n; ++i) {
            int c = __shfl(ep.x, i); float w = __int_as_float(__shfl(ep.y, i));
            a0 = fmaf(w, bf2f(h[(size_t)c * DH + lane]), a0);
        }
    }
    float res = ((a0 + a1) + (a2 + a3)) + ((a4 + a5) + (a6 + a7));
    y[(size_t)r * DH + lane] = f2bf(res);
}

// ---- weight prep: Wt[n][192] bf16, k = j*64+kin ----
// j=0: W[0]-W[2]; j=1: W[1]; j=2: 2*W[2]   (folds Tx2 = 2*y2 - Tx0 into weights)
__global__ void wprep_kernel(const float* __restrict__ W, int SW,
                             unsigned short* __restrict__ Wt) {
    int idx = blockIdx.x * 256 + threadIdx.x;
    if (idx >= 64 * 192) return;
    int n = idx / 192, k = idx - n * 192;
    int j = k >> 6, kin = k & 63;
    float v = 0.f;
    if (n < SW) {
        if (j == 0)      v = W[kin * SW + n] - W[2 * 64 * SW + kin * SW + n];
        else if (j == 1) v = W[64 * SW + kin * SW + n];
        else             v = 2.f * W[2 * 64 * SW + kin * SW + n];
    }
    Wt[n * 192 + k] = f2bf(v);
}

// ---- MFMA GEMM: out = relu(h@Wt_j0 + y1@Wt_j1 + y2@Wt_j2 + b) ----
template<int SW, int NT, int OBF>
__global__ __launch_bounds__(256)
void gemm3_mfma_kernel(const unsigned short* __restrict__ h,
                       const unsigned short* __restrict__ y1,
                       const unsigned short* __restrict__ y2,
                       const unsigned short* __restrict__ Wt,
                       const float* __restrict__ bg, void* __restrict__ outg) {
    int tid = threadIdx.x;
    int w = tid >> 6, l = tid & 63;
    int m = l & 15, kg = l >> 4;
    int node = blockIdx.x * 64 + w * 16 + m;
    int nclamp = node < NN ? node : NN - 1;

    f32x4 acc[NT];
    #pragma unroll
    for (int t = 0; t < NT; ++t) acc[t] = (f32x4){0.f, 0.f, 0.f, 0.f};

    #pragma unroll
    for (int ks = 0; ks < 6; ++ks) {
        const unsigned short* src = (ks < 2) ? h : (ks < 4 ? y1 : y2);
        int kin = (ks & 1) * 32 + kg * 8;
        bf16x8 af = *(const bf16x8*)(src + (size_t)nclamp * DH + kin);
        #pragma unroll
        for (int t = 0; t < NT; ++t) {
            const bf16x8* pb = (const bf16x8*)(Wt + ((size_t)(t * 16 + m) * 192 + ks * 32 + kg * 8));
            acc[t] = __builtin_amdgcn_mfma_f32_16x16x32_bf16(af, *pb, acc[t], 0, 0, 0);
        }
    }

    int orow = blockIdx.x * 64 + w * 16 + kg * 4;   // + r
    #pragma unroll
    for (int t = 0; t < NT; ++t) {
        int oc = t * 16 + m;
        float bias = (oc < SW) ? bg[oc] : 0.f;
        #pragma unroll
        for (int r = 0; r < 4; ++r) {
            int nd = orow + r;
            if (nd < NN && oc < SW) {
                float v = fmaxf(acc[t][r] + bias, 0.f);
                if (OBF) ((unsigned short*)outg)[(size_t)nd * SW + oc] = f2bf(v);
                else     ((float*)outg)[(size_t)nd * SW + oc] = v;
            }
        }
    }
}

// ---- in-place log_softmax over last dim (40) ----
__global__ void lsm_kernel(float* __restrict__ out) {
    int g = blockIdx.x * blockDim.x + threadIdx.x;
    int node = g >> 6, lane = g & 63;
    if (node >= NN) return;
    float v = lane < DO ? out[node * DO + lane] : -INFINITY;
    float m = v;
    #pragma unroll
    for (int off = 32; off > 0; off >>= 1) m = fmaxf(m, __shfl_xor(m, off));
    float ex = lane < DO ? __expf(v - m) : 0.f;
    float s = ex;
    #pragma unroll
    for (int off = 32; off > 0; off >>= 1) s += __shfl_xor(s, off);
    if (lane < DO) out[node * DO + lane] = v - m - __logf(s);
}

extern "C" void kernel_launch(void* const* d_in, const int* in_sizes, int n_in,
                              void* d_out, int out_size, void* d_ws, size_t ws_size,
                              hipStream_t stream) {
    const float* x  = (const float*)d_in[0];
    const int*   ei = (const int*)d_in[1];
    const float* ea = (const float*)d_in[2];
    const float* W0 = (const float*)d_in[3];
    const float* b0 = (const float*)d_in[4];
    const float* W1 = (const float*)d_in[5];
    const float* b1 = (const float*)d_in[6];
    const float* W2 = (const float*)d_in[7];
    const float* b2 = (const float*)d_in[8];
    float* out = (float*)d_out;

    const int* row = ei;
    const int* col = ei + NE;

    const size_t HB2 = (size_t)NN * DH * 2;     // bf16 node-feature buffer
    char* p = (char*)d_ws;
    int*   ptr    = (int*)p;  p += (size_t)(NN + 4) * 4;
    int2*  epack  = (int2*)p; p += (size_t)NE * 8;
    int2*  binned = (int2*)p; p += (size_t)NE * 8;
    float* dinv   = (float*)p; p += (size_t)NN * 4;
    int*   bcnt   = (int*)p;  p += (size_t)(NBKT + 4) * 4;
    int*   bbase  = (int*)p;  p += (size_t)(NBKT + 4) * 4;
    int*   gcur   = (int*)p;  p += (size_t)(NBKT + 4) * 4;
    unsigned short* xb  = (unsigned short*)p; p += HB2;
    unsigned short* y1b = (unsigned short*)p; p += HB2;
    unsigned short* y2b = (unsigned short*)p; p += HB2;
    unsigned short* hAb = (unsigned short*)p; p += HB2;
    unsigned short* hBb = (unsigned short*)p; p += HB2;
    unsigned short* Wt0 = (unsigned short*)p; p += (size_t)64 * 192 * 2;
    unsigned short* Wt1 = (unsigned short*)p; p += (size_t)64 * 192 * 2;
    unsigned short* Wt2 = (unsigned short*)p; p += (size_t)64 * 192 * 2;

    // ---- weight prep + x conversion (tiny) ----
    wprep_kernel<<<48, 256, 0, stream>>>(W0, 64, Wt0);
    wprep_kernel<<<48, 256, 0, stream>>>(W1, 64, Wt1);
    wprep_kernel<<<48, 256, 0, stream>>>(W2, 40, Wt2);
    x2bf_kernel<<<(NN * DH / 4 + 255) / 256, 256, 0, stream>>>(x, xb);

    // ---- binned CSR build (~200K global atomics instead of 1.6M) ----
    hipMemsetAsync(bcnt, 0, (size_t)NBKT * 4, stream);
    bin_count_kernel<<<P3B, 1024, 0, stream>>>(row, bcnt);
    bscan_kernel<<<1, 512, 0, stream>>>(bcnt, bbase, gcur, ptr);
    bin_scatter_kernel<<<P3B, 1024, 0, stream>>>(row, col, ea, gcur, binned);
    bfin_kernel<<<NBKT, 1024, 0, stream>>>(bbase, binned, ptr, dinv, epack);
    env_kernel<<<(NE + 255) / 256, 256, 0, stream>>>(dinv, epack);

    const int SPMV_GRID = (NN * 64 + 255) / 256;
    const int GEMM_GRID = (NN + 63) / 64;

    // ---- layer 0 (h = xb) ----
    spmv_csr_kernel<<<SPMV_GRID, 256, 0, stream>>>(ptr, epack, xb, y1b);
    spmv_csr_kernel<<<SPMV_GRID, 256, 0, stream>>>(ptr, epack, y1b, y2b);
    gemm3_mfma_kernel<64, 4, 1><<<GEMM_GRID, 256, 0, stream>>>(xb, y1b, y2b, Wt0, b0, hAb);

    // ---- layer 1 (h = hAb) ----
    spmv_csr_kernel<<<SPMV_GRID, 256, 0, stream>>>(ptr, epack, hAb, y1b);
    spmv_csr_kernel<<<SPMV_GRID, 256, 0, stream>>>(ptr, epack, y1b, y2b);
    gemm3_mfma_kernel<64, 4, 1><<<GEMM_GRID, 256, 0, stream>>>(hAb, y1b, y2b, Wt1, b1, hBb);

    // ---- layer 2 (h = hBb) -> f32 logits into d_out ----
    spmv_csr_kernel<<<SPMV_GRID, 256, 0, stream>>>(ptr, epack, hBb, y1b);
    spmv_csr_kernel<<<SPMV_GRID, 256, 0, stream>>>(ptr, epack, y1b, y2b);
    gemm3_mfma_kernel<40, 3, 0><<<GEMM_GRID, 256, 0, stream>>>(hBb, y1b, y2b, Wt2, b2, out);

    // ---- log_softmax in place ----
    lsm_kernel<<<(NN * 64 + 255) / 256, 256, 0, stream>>>(out);
}